// Round 3
// baseline (6254.697 us; speedup 1.0000x reference)
//
#include <hip/hip_runtime.h>
#include <hip/hip_bf16.h>

#define Bx 256
#define Tx 512
#define Ex 768
#define Hx 256
#define Gx 1024
#define Vx 7987
#define TCx 32
#define NCHx 16

typedef unsigned short u16;
typedef unsigned int u32;
typedef __bf16 bf16;
typedef bf16 bf16x8 __attribute__((ext_vector_type(8)));
typedef float f32x4 __attribute__((ext_vector_type(4)));

__device__ __forceinline__ u16 f2bf(float f) {
  union { float f; u32 u; } x; x.f = f;
  u32 r = x.u + 0x7fffu + ((x.u >> 16) & 1u);
  return (u16)(r >> 16);
}
__device__ __forceinline__ float bf2f(u16 b) {
  union { u32 u; float f; } x; x.u = ((u32)b) << 16;
  return x.f;
}
__device__ __forceinline__ void gload16(const void* g, void* l) {
  __builtin_amdgcn_global_load_lds((const __attribute__((address_space(1))) u32*)g,
                                   (__attribute__((address_space(3))) u32*)l, 16, 0, 0);
}
// sigmoid via exp2 + rcp (NaN-free for any finite x)
__device__ __forceinline__ float sigf(float x) {
  return __builtin_amdgcn_rcpf(1.f + __builtin_amdgcn_exp2f(x * -1.442695041f));
}
// raw barrier: drain LDS ops only, leave global loads in flight
__device__ __forceinline__ void bar_ds() {
  __builtin_amdgcn_sched_barrier(0);
  asm volatile("s_waitcnt lgkmcnt(0)" ::: "memory");
  __builtin_amdgcn_s_barrier();
  __builtin_amdgcn_sched_barrier(0);
}

// ---------------- conversion / packing kernels ----------------

__global__ void k_cvt(const float* __restrict__ src, u16* __restrict__ dst, int n) {
  int i = blockIdx.x * blockDim.x + threadIdx.x;
  int st = gridDim.x * blockDim.x;
  for (; i < n; i += st) dst[i] = f2bf(src[i]);
}

__global__ void k_bias(const float* __restrict__ bihf, const float* __restrict__ bhhf,
                       const float* __restrict__ bihb, const float* __restrict__ bhhb,
                       float* __restrict__ bcat) {
  int i = blockIdx.x * blockDim.x + threadIdx.x;
  if (i < Gx) { bcat[i] = bihf[i] + bhhf[i]; bcat[Gx + i] = bihb[i] + bhhb[i]; }
}

// pack w_hh into fragment-linear layout:
// pk[((dir*8 + kc)*64 + nblk)*512 + lane*8 + j] = w[dir][n=nblk*16+(lane&15)][k=kc*32+(lane>>4)*8+j]
__global__ void k_pack_whh(const float* __restrict__ wf, const float* __restrict__ wb,
                           u16* __restrict__ pk) {
  int i = blockIdx.x * blockDim.x + threadIdx.x;
  int st = gridDim.x * blockDim.x;
  for (; i < 2 * 8 * 64 * 512; i += st) {
    int j = i & 7;
    int lane = (i >> 3) & 63;
    int nblk = (i >> 9) & 63;
    int kc = (i >> 15) & 7;
    int dir = i >> 18;
    int n = nblk * 16 + (lane & 15);
    int k = kc * 32 + ((lane >> 4) << 3) + j;
    const float* w = dir ? wb : wf;
    pk[i] = f2bf(w[n * Hx + k]);
  }
}

// ---------------- input projection GEMM (per time-chunk) ----------------
// BLOCKED output: xp[((dir*64 + slice)*TCx + t)*4096 + ch*4 + bi]
//   slice = b>>2, bi = b&3, ch = col&1023, dir = col>>10, m = t*256 + b
__global__ __launch_bounds__(256) void k_xproj(
    const u16* __restrict__ embbf, const u16* __restrict__ wih,
    const int* __restrict__ input, const float* __restrict__ bcat,
    u16* __restrict__ xp, int t0) {
  __shared__ u16 sA[128 * 64];
  __shared__ u16 sB[128 * 64];
  const int tid = threadIdx.x;
  const int l = tid & 63, w = tid >> 6;
  const int bx = blockIdx.x & 15, by = blockIdx.x >> 4;
  const int wm = w >> 1, wn = w & 1;
  const int lr = l >> 3, lc = l & 7;

  f32x4 acc[4][4];
#pragma unroll
  for (int a = 0; a < 4; ++a)
#pragma unroll
    for (int b = 0; b < 4; ++b) acc[a][b] = f32x4{0.f, 0.f, 0.f, 0.f};

  size_t asrc[4], bsrc[4];
#pragma unroll
  for (int j = 0; j < 4; ++j) {
    int row = j * 32 + w * 8 + lr;
    int m = by * 128 + row;
    int b = m & 255, tt = m >> 8;           // m = t_local*256 + b
    int er = input[b * Tx + t0 + tt];
    asrc[j] = (size_t)er * (Ex * 2) + (size_t)((lc * 16) ^ ((row & 7) << 4));
    bsrc[j] = (size_t)(bx * 128 + row) * (Ex * 2) + (size_t)((lc * 16) ^ ((row & 7) << 4));
  }

  for (int kt = 0; kt < 12; ++kt) {
    const char* ebase = (const char*)embbf + (size_t)kt * 128;
    const char* wbase = (const char*)wih + (size_t)kt * 128;
#pragma unroll
    for (int j = 0; j < 4; ++j) {
      gload16(ebase + asrc[j], (char*)sA + (j * 32 + w * 8) * 128);
      gload16(wbase + bsrc[j], (char*)sB + (j * 32 + w * 8) * 128);
    }
    __syncthreads();
#pragma unroll
    for (int kk = 0; kk < 2; ++kk) {
      int kb = kk * 64 + ((l >> 4) * 16);
      bf16x8 av[4], bv[4];
#pragma unroll
      for (int f = 0; f < 4; ++f) {
        int r = wm * 64 + f * 16 + (l & 15);
        av[f] = *(const bf16x8*)((const char*)sA + r * 128 + (kb ^ ((r & 7) << 4)));
      }
#pragma unroll
      for (int f = 0; f < 4; ++f) {
        int n = wn * 64 + f * 16 + (l & 15);
        bv[f] = *(const bf16x8*)((const char*)sB + n * 128 + (kb ^ ((n & 7) << 4)));
      }
#pragma unroll
      for (int fm = 0; fm < 4; ++fm)
#pragma unroll
        for (int fn = 0; fn < 4; ++fn)
          acc[fm][fn] = __builtin_amdgcn_mfma_f32_16x16x32_bf16(av[fm], bv[fn], acc[fm][fn], 0, 0, 0);
    }
    __syncthreads();
  }
  // epilogue: add bias, store bf16 to blocked layout
#pragma unroll
  for (int fn = 0; fn < 4; ++fn) {
    int col = bx * 128 + wn * 64 + fn * 16 + (l & 15);
    int dirc = col >> 10, ch = col & 1023;
    float bias = bcat[col];
#pragma unroll
    for (int fm = 0; fm < 4; ++fm) {
      int m0 = by * 128 + wm * 64 + fm * 16 + ((l >> 4) << 2);
      int b = m0 & 255, t = m0 >> 8;
      ushort4 v;
      v.x = f2bf(acc[fm][fn][0] + bias);
      v.y = f2bf(acc[fm][fn][1] + bias);
      v.z = f2bf(acc[fm][fn][2] + bias);
      v.w = f2bf(acc[fm][fn][3] + bias);
      *(ushort4*)(xp + (size_t)(((dirc * 64 + (b >> 2)) * TCx + t)) * 4096 + ch * 4) = v;
    }
  }
}

// ---------------- recurrence (per time-chunk) ----------------
// 128 blocks = 2 dirs x 64 batch-slices (4 rows each). 8 waves, 512 thr.
// ALL w_hh chunks register-resident (256 regs/thread -> VGPR+AGPR unified file).
// LDS holds only the h exchange buffer. c-state is lane-private registers.
#define XQL(dst, tt)                                                          \
  _Pragma("unroll") for (int i = 0; i < 8; ++i)                               \
      dst[i] = *(const ushort4*)(xbb + (tt) * 4096 + xqo[i]);

#define STEP(xq, tcur, tnext) {                                               \
  f32x4 acc[4][2];                                                            \
  _Pragma("unroll") for (int i = 0; i < 8; ++i)                               \
    acc[i >> 1][i & 1] = f32x4{bf2f(xq[i].x), bf2f(xq[i].y),                  \
                               bf2f(xq[i].z), bf2f(xq[i].w)};                 \
  XQL(xq, tnext);                                                             \
  bf16x8 av[8];                                                               \
  _Pragma("unroll") for (int c = 0; c < 8; ++c)                               \
    av[c] = *(const bf16x8*)(shr + c * 32);                                   \
  bar_ds(); /* B1: all A-reads of this step retired */                        \
  _Pragma("unroll") for (int c = 0; c < 8; ++c)                               \
    _Pragma("unroll") for (int nt = 0; nt < 8; ++nt)                          \
      acc[nt >> 1][nt & 1] = __builtin_amdgcn_mfma_f32_16x16x32_bf16(         \
          av[c], wres[c][nt], acc[nt >> 1][nt & 1], 0, 0, 0);                 \
  {                                                                           \
    const int tg = t0 + (tcur);                                               \
    _Pragma("unroll") for (int fc = 0; fc < 2; ++fc)                          \
      _Pragma("unroll") for (int r = 0; r < 4; ++r) {                         \
        float cold = creg[fc][r];                                             \
        float si = sigf(acc[0][fc][r]);                                       \
        float sf = sigf(acc[1][fc][r]);                                       \
        float tv = 2.f * sigf(2.f * acc[2][fc][r]) - 1.f;                     \
        float so = sigf(acc[3][fc][r]);                                       \
        float cn = sf * cold + si * tv;                                       \
        float hn = so * (2.f * sigf(2.f * cn) - 1.f);                         \
        creg[fc][r] = cn;                                                     \
        hreg[fc][r] = hn;                                                     \
        if (lv && tg == tgt[r])                                               \
          gath[(size_t)(b0 + r) * 512 + dir * 256 + w * 32 + fc * 16 + l] = hn; \
      }                                                                       \
  }                                                                           \
  _Pragma("unroll") for (int fc = 0; fc < 2; ++fc)                            \
    _Pragma("unroll") for (int r = 0; r < 4; ++r)                             \
      sh[(((l >> 4) << 2) + r) * 264 + w * 32 + fc * 16 + (l & 15)] =         \
          lv ? f2bf(hreg[fc][r]) : (u16)0;                                    \
  bar_ds(); /* B2: h writes visible for next step */                          \
}

__global__ __launch_bounds__(512, 2) void k_rnn(
    const u16* __restrict__ wpk_all, const u16* __restrict__ xp,
    const int* __restrict__ target, float* __restrict__ hst,
    float* __restrict__ cst, float* __restrict__ gath, int t0) {
  __shared__ u16 sh[16 * 264];
  const int tid = threadIdx.x;
  const int l = tid & 63, w = tid >> 6;
  const int dir = blockIdx.x >> 6, slice = blockIdx.x & 63;
  const int b0 = slice * 4;
  const int lv = (l < 16);
  const u16* wpkd = wpk_all + (size_t)dir * 262144;
  const u16* wbase = wpkd + w * 1024 + l * 8;

  // all 8 kc chunks of w_hh -> registers (B-fragments, 256 regs/thread)
  bf16x8 wres[8][8];
#pragma unroll
  for (int c = 0; c < 8; ++c)
#pragma unroll
    for (int nt = 0; nt < 8; ++nt)
      wres[c][nt] = *(const bf16x8*)(wbase + c * 32768 + (nt >> 1) * 8192 + (nt & 1) * 512);

  // h state -> LDS rows 0-3 (bf16); rows 4-15 zeroed (padding for M=16 MFMA)
  {
    int su = (tid & 31) * 8;
    if (tid < 128) {
      int srow = tid >> 5;
      const float* hsrc = hst + (size_t)(dir * Bx + b0 + srow) * Hx + su;
#pragma unroll
      for (int j2 = 0; j2 < 8; ++j2) sh[srow * 264 + su + j2] = f2bf(hsrc[j2]);
    } else {
      int rr = 4 + ((tid - 128) >> 5);
#pragma unroll
      for (int j2 = 0; j2 < 8; ++j2) sh[rr * 264 + su + j2] = 0;
    }
  }
  // c state -> lane-private registers (rows 0-3 on lanes l<16; rest dummy)
  float creg[2][4], hreg[2][4];
#pragma unroll
  for (int fc = 0; fc < 2; ++fc)
#pragma unroll
    for (int r = 0; r < 4; ++r) {
      int row = ((l >> 4) << 2) + r;
      int br = dir * Bx + b0 + (row & 3);
      creg[fc][r] = cst[(size_t)br * Hx + w * 32 + fc * 16 + (l & 15)];
      hreg[fc][r] = 0.f;
    }
  int tgt[4];
#pragma unroll
  for (int r = 0; r < 4; ++r) tgt[r] = target[b0 + r];

  // xp prefetch (blocked layout): per (g,fc) a wave reads 128 contiguous bytes
  int xqo[8];
#pragma unroll
  for (int i = 0; i < 8; ++i)
    xqo[i] = ((i >> 1) * 256 + w * 32 + (i & 1) * 16 + (l & 15)) * 4;
  const u16* xbb = xp + (size_t)((dir * 64 + slice) * TCx) * 4096;
  ushort4 xqA[8], xqB[8];
  XQL(xqA, 0);
  XQL(xqB, 1);

  const u16* shr = sh + (l & 15) * 264 + ((l >> 4) << 3);
  __syncthreads();

#pragma unroll 1
  for (int tt = 0; tt < TCx; tt += 2) {
    STEP(xqA, tt, (tt + 2 < TCx) ? tt + 2 : tt);
    STEP(xqB, tt + 1, (tt + 3 < TCx) ? tt + 3 : tt + 1);
  }

  // writeback state for next chunk (f32; next chunk re-rounds h identically)
  if (lv) {
#pragma unroll
    for (int fc = 0; fc < 2; ++fc)
#pragma unroll
      for (int r = 0; r < 4; ++r) {
        int u = w * 32 + fc * 16 + l;
        hst[(size_t)(dir * Bx + b0 + r) * Hx + u] = hreg[fc][r];
        cst[(size_t)(dir * Bx + b0 + r) * Hx + u] = creg[fc][r];
      }
  }
}

// ---------------- output head ----------------
__global__ void k_out(const float* __restrict__ gath, const float* __restrict__ wout,
                      const float* __restrict__ bout, float* __restrict__ out) {
  int b = blockIdx.x, l = threadIdx.x;
  float s = 0.f;
  for (int j = l; j < 512; j += 64) s += gath[(size_t)b * 512 + j] * wout[j];
#pragma unroll
  for (int off = 32; off; off >>= 1) s += __shfl_down(s, off);
  if (l == 0) out[b] = 1.f / (1.f + __expf(-(s + bout[0])));
}

extern "C" void kernel_launch(void* const* d_in, const int* in_sizes, int n_in,
                              void* d_out, int out_size, void* d_ws, size_t ws_size,
                              hipStream_t stream) {
  const int* input = (const int*)d_in[0];
  const int* target = (const int*)d_in[1];
  const float* emb  = (const float*)d_in[3];
  const float* wihf = (const float*)d_in[4];
  const float* whhf = (const float*)d_in[5];
  const float* bihf = (const float*)d_in[6];
  const float* bhhf = (const float*)d_in[7];
  const float* wihb = (const float*)d_in[8];
  const float* whhb = (const float*)d_in[9];
  const float* bihb = (const float*)d_in[10];
  const float* bhhb = (const float*)d_in[11];
  const float* wout = (const float*)d_in[12];
  const float* bout = (const float*)d_in[13];
  float* out = (float*)d_out;

  char* ws = (char*)d_ws;
  u16* embbf  = (u16*)(ws + 0);          // 12,268,032 B
  u16* wih    = (u16*)(ws + 12268032);   //  3,145,728 B  [2048][768] bf16
  u16* wpk    = (u16*)(ws + 15413760);   //  1,048,576 B  packed w_hh
  float* bcat = (float*)(ws + 16462336); //      8,192 B
  float* hst  = (float*)(ws + 16470528); //    524,288 B
  float* cst  = (float*)(ws + 16994816); //    524,288 B
  float* gath = (float*)(ws + 17519104); //    524,288 B
  u16* xp     = (u16*)(ws + 18043392);   // 33,554,432 B  blocked [dir*64+slice][t][4096]

  hipMemsetAsync(hst, 0, 524288 * 2, stream);  // zero h and c state
  k_cvt<<<1024, 256, 0, stream>>>(emb, embbf, Vx * Ex);
  k_cvt<<<512, 256, 0, stream>>>(wihf, wih, Gx * Ex);
  k_cvt<<<512, 256, 0, stream>>>(wihb, wih + Gx * Ex, Gx * Ex);
  k_bias<<<4, 256, 0, stream>>>(bihf, bhhf, bihb, bhhb, bcat);
  k_pack_whh<<<512, 256, 0, stream>>>(whhf, whhb, wpk);

  for (int c = 0; c < NCHx; ++c) {
    k_xproj<<<1024, 256, 0, stream>>>(embbf, wih, input, bcat, xp, c * TCx);
    k_rnn<<<128, 512, 0, stream>>>(wpk, xp, target, hst, cst, gath, c * TCx);
  }
  k_out<<<256, 64, 0, stream>>>(gath, wout, bout, out);
}

// Round 4
// 2452.798 us; speedup vs baseline: 2.5500x; 2.5500x over previous
//
#include <hip/hip_runtime.h>
#include <hip/hip_bf16.h>

#define Bx 256
#define Tx 512
#define Ex 768
#define Hx 256
#define Gx 1024
#define Vx 7987
#define VPAD 8064  // 63*128

typedef unsigned short u16;
typedef unsigned int u32;
typedef __bf16 bf16;
typedef bf16 bf16x8 __attribute__((ext_vector_type(8)));
typedef u16 u16x8 __attribute__((ext_vector_type(8)));
typedef float f32x4 __attribute__((ext_vector_type(4)));

__device__ __forceinline__ u16 f2bf(float f) {
  union { float f; u32 u; } x; x.f = f;
  u32 r = x.u + 0x7fffu + ((x.u >> 16) & 1u);
  return (u16)(r >> 16);
}
__device__ __forceinline__ float bf2f(u16 b) {
  union { u32 u; float f; } x; x.u = ((u32)b) << 16;
  return x.f;
}
__device__ __forceinline__ void gload16(const void* g, void* l) {
  __builtin_amdgcn_global_load_lds((const __attribute__((address_space(1))) u32*)g,
                                   (__attribute__((address_space(3))) u32*)l, 16, 0, 0);
}
__device__ __forceinline__ float sigf(float x) {
  return __builtin_amdgcn_rcpf(1.f + __builtin_amdgcn_exp2f(x * -1.442695041f));
}
// barrier draining LDS ops only; global loads stay in flight
__device__ __forceinline__ void bar_ds() {
  __builtin_amdgcn_sched_barrier(0);
  asm volatile("s_waitcnt lgkmcnt(0)" ::: "memory");
  __builtin_amdgcn_s_barrier();
  __builtin_amdgcn_sched_barrier(0);
}

// ---------------- conversion / packing kernels ----------------

__global__ void k_cvt(const float* __restrict__ src, u16* __restrict__ dst, int n) {
  int i = blockIdx.x * blockDim.x + threadIdx.x;
  int st = gridDim.x * blockDim.x;
  for (; i < n; i += st) dst[i] = f2bf(src[i]);
}

__global__ void k_bias(const float* __restrict__ bihf, const float* __restrict__ bhhf,
                       const float* __restrict__ bihb, const float* __restrict__ bhhb,
                       float* __restrict__ bcat) {
  int i = blockIdx.x * blockDim.x + threadIdx.x;
  if (i < Gx) { bcat[i] = bihf[i] + bhhf[i]; bcat[Gx + i] = bihb[i] + bhhb[i]; }
}

// pack w_hh into fragment-linear layout:
// pk[((dir*8 + kc)*64 + nblk)*512 + lane*8 + j] = w[dir][n=nblk*16+(lane&15)][k=kc*32+(lane>>4)*8+j]
__global__ void k_pack_whh(const float* __restrict__ wf, const float* __restrict__ wb,
                           u16* __restrict__ pk) {
  int i = blockIdx.x * blockDim.x + threadIdx.x;
  int st = gridDim.x * blockDim.x;
  for (; i < 2 * 8 * 64 * 512; i += st) {
    int j = i & 7;
    int lane = (i >> 3) & 63;
    int nblk = (i >> 9) & 63;
    int kc = (i >> 15) & 7;
    int dir = i >> 18;
    int n = nblk * 16 + (lane & 15);
    int k = kc * 32 + ((lane >> 4) << 3) + j;
    const float* w = dir ? wb : wf;
    pk[i] = f2bf(w[n * Hx + k]);
  }
}

// ---------------- vocab projection GEMM (runs ONCE) ----------------
// vp[(tok*2 + dir)*1024 + (w*16 + u)*8 + g*2 + fc] = emb[tok] @ wih[col]^T + bias
// where col = dir*1024 + g*256 + w*32 + fc*16 + u
__global__ __launch_bounds__(256) void k_vproj(
    const u16* __restrict__ embbf, const u16* __restrict__ wih,
    const float* __restrict__ bcat, u16* __restrict__ vp) {
  __shared__ u16 sA[128 * 64];
  __shared__ u16 sB[128 * 64];
  const int tid = threadIdx.x;
  const int l = tid & 63, w = tid >> 6;
  const int bx = blockIdx.x & 15, by = blockIdx.x >> 4;  // by: 0..62
  const int wm = w >> 1, wn = w & 1;
  const int lr = l >> 3, lc = l & 7;

  f32x4 acc[4][4];
#pragma unroll
  for (int a = 0; a < 4; ++a)
#pragma unroll
    for (int b = 0; b < 4; ++b) acc[a][b] = f32x4{0.f, 0.f, 0.f, 0.f};

  size_t asrc[4], bsrc[4];
#pragma unroll
  for (int j = 0; j < 4; ++j) {
    int row = j * 32 + w * 8 + lr;
    int m = by * 128 + row;
    int er = (m < Vx) ? m : 0;  // clamp pad rows
    asrc[j] = (size_t)er * (Ex * 2) + (size_t)((lc * 16) ^ ((row & 7) << 4));
    bsrc[j] = (size_t)(bx * 128 + row) * (Ex * 2) + (size_t)((lc * 16) ^ ((row & 7) << 4));
  }

  for (int kt = 0; kt < 12; ++kt) {
    const char* ebase = (const char*)embbf + (size_t)kt * 128;
    const char* wbase = (const char*)wih + (size_t)kt * 128;
#pragma unroll
    for (int j = 0; j < 4; ++j) {
      gload16(ebase + asrc[j], (char*)sA + (j * 32 + w * 8) * 128);
      gload16(wbase + bsrc[j], (char*)sB + (j * 32 + w * 8) * 128);
    }
    __syncthreads();
#pragma unroll
    for (int kk = 0; kk < 2; ++kk) {
      int kb = kk * 64 + ((l >> 4) * 16);
      bf16x8 av[4], bv[4];
#pragma unroll
      for (int f = 0; f < 4; ++f) {
        int r = wm * 64 + f * 16 + (l & 15);
        av[f] = *(const bf16x8*)((const char*)sA + r * 128 + (kb ^ ((r & 7) << 4)));
      }
#pragma unroll
      for (int f = 0; f < 4; ++f) {
        int n = wn * 64 + f * 16 + (l & 15);
        bv[f] = *(const bf16x8*)((const char*)sB + n * 128 + (kb ^ ((n & 7) << 4)));
      }
#pragma unroll
      for (int fm = 0; fm < 4; ++fm)
#pragma unroll
        for (int fn = 0; fn < 4; ++fn)
          acc[fm][fn] = __builtin_amdgcn_mfma_f32_16x16x32_bf16(av[fm], bv[fn], acc[fm][fn], 0, 0, 0);
    }
    __syncthreads();
  }
  // epilogue: bias + packed scatter store
#pragma unroll
  for (int fn = 0; fn < 4; ++fn) {
    int col = bx * 128 + wn * 64 + fn * 16 + (l & 15);
    int dirc = col >> 10, c10 = col & 1023;
    int gq = c10 >> 8, wq = (c10 >> 5) & 7, fcq = (c10 >> 4) & 1, uq = c10 & 15;
    int pos = (wq * 16 + uq) * 8 + gq * 2 + fcq;
    float bias = bcat[col];
#pragma unroll
    for (int fm = 0; fm < 4; ++fm) {
      int m0 = by * 128 + wm * 64 + fm * 16 + ((l >> 4) << 2);
#pragma unroll
      for (int r = 0; r < 4; ++r)
        vp[((size_t)(m0 + r) * 2 + dirc) * 1024 + pos] = f2bf(acc[fm][fn][r] + bias);
    }
  }
}

// ---------------- recurrence: ONE launch, all 512 steps ----------------
// 32 blocks = 2 dirs x 16 batch-slices (16 rows). 8 waves, 512 thr.
// Weights: kc0-3 regs (128 VGPR), kc4-5 LDS (128 KB), kc6-7 one streamed slot.
// h: double-buffered XOR-swizzled LDS (1 barrier/step). c: LDS. x: vproj gather.
#define RSTEP(IDB, T, RB, WB) {                                               \
  f32x4 acc[4][2];                                                            \
  _Pragma("unroll") for (int g = 0; g < 4; ++g)                               \
    _Pragma("unroll") for (int fc = 0; fc < 2; ++fc)                          \
      acc[g][fc] = f32x4{bf2f(xv[0][g * 2 + fc]), bf2f(xv[1][g * 2 + fc]),    \
                         bf2f(xv[2][g * 2 + fc]), bf2f(xv[3][g * 2 + fc])};   \
  _Pragma("unroll") for (int r = 0; r < 4; ++r)                               \
    xv[r] = *(const u16x8*)(vp + ((size_t)(IDB[r] * 2 + dir)) * 1024 + go);   \
  { int tc = (T) + 3 < Tx ? (T) + 3 : Tx - 1;                                 \
    _Pragma("unroll") for (int r = 0; r < 4; ++r) IDB[r] = ip[r * Tx + tc]; } \
  { bf16x8 a = *(const bf16x8*)((RB) + aoff[7]);                              \
    _Pragma("unroll") for (int nt = 0; nt < 8; ++nt)                          \
      acc[nt >> 1][nt & 1] = __builtin_amdgcn_mfma_f32_16x16x32_bf16(         \
          a, wslot[nt], acc[nt >> 1][nt & 1], 0, 0, 0); }                     \
  _Pragma("unroll") for (int nt = 0; nt < 8; ++nt)                            \
    wslot[nt] = *(const bf16x8*)(wbase + 6 * 32768 + (nt >> 1) * 8192 + (nt & 1) * 512); \
  _Pragma("unroll") for (int c = 0; c < 4; ++c) {                             \
    bf16x8 a = *(const bf16x8*)((RB) + aoff[c]);                              \
    _Pragma("unroll") for (int nt = 0; nt < 8; ++nt)                          \
      acc[nt >> 1][nt & 1] = __builtin_amdgcn_mfma_f32_16x16x32_bf16(         \
          a, wres[c][nt], acc[nt >> 1][nt & 1], 0, 0, 0); }                   \
  _Pragma("unroll") for (int c = 0; c < 2; ++c) {                             \
    bf16x8 a = *(const bf16x8*)((RB) + aoff[4 + c]);                          \
    _Pragma("unroll") for (int nt = 0; nt < 8; ++nt) {                        \
      bf16x8 bb = *(const bf16x8*)(swb + c * 32768 + (nt >> 1) * 8192 + (nt & 1) * 512); \
      acc[nt >> 1][nt & 1] = __builtin_amdgcn_mfma_f32_16x16x32_bf16(         \
          a, bb, acc[nt >> 1][nt & 1], 0, 0, 0); } }                          \
  { bf16x8 a = *(const bf16x8*)((RB) + aoff[6]);                              \
    _Pragma("unroll") for (int nt = 0; nt < 8; ++nt)                          \
      acc[nt >> 1][nt & 1] = __builtin_amdgcn_mfma_f32_16x16x32_bf16(         \
          a, wslot[nt], acc[nt >> 1][nt & 1], 0, 0, 0); }                     \
  _Pragma("unroll") for (int nt = 0; nt < 8; ++nt)                            \
    wslot[nt] = *(const bf16x8*)(wbase + 7 * 32768 + (nt >> 1) * 8192 + (nt & 1) * 512); \
  _Pragma("unroll") for (int fc = 0; fc < 2; ++fc) {                          \
    int u = w * 32 + fc * 16 + (l & 15);                                      \
    _Pragma("unroll") for (int r = 0; r < 4; ++r) {                           \
      int row = rr + r;                                                       \
      float cold = cl[row * 256 + u];                                         \
      float si = sigf(acc[0][fc][r]);                                         \
      float sf = sigf(acc[1][fc][r]);                                         \
      float tv = 2.f * sigf(2.f * acc[2][fc][r]) - 1.f;                       \
      float so = sigf(acc[3][fc][r]);                                         \
      float cn = sf * cold + si * tv;                                         \
      float hn = so * (2.f * sigf(2.f * cn) - 1.f);                           \
      cl[row * 256 + u] = cn;                                                 \
      if ((T) == tgt[r]) gath[(size_t)(b0 + row) * 512 + dir * 256 + u] = hn; \
      *(u16*)((WB) + row * 512 + ((u * 2) ^ ((row & 7) << 4))) = f2bf(hn);    \
    }                                                                         \
  }                                                                           \
  bar_ds();                                                                   \
}

__global__ __launch_bounds__(512, 2) void k_rnn(
    const u16* __restrict__ wpk_all, const u16* __restrict__ vp,
    const int* __restrict__ input, const int* __restrict__ target,
    float* __restrict__ gath) {
  __shared__ u16 swr[65536];    // 131072 B: kc4,5
  __shared__ u16 shd[2][4096];  // 2 x 8192 B: h, XOR-swizzled
  __shared__ float cl[16 * 256];// 16384 B: c
  const int tid = threadIdx.x;
  const int l = tid & 63, w = tid >> 6;
  const int dir = blockIdx.x >> 4, slice = blockIdx.x & 15;
  const int b0 = slice * 16;
  const int rr = (l >> 4) << 2;
  const u16* wpkd = wpk_all + (size_t)dir * 262144;
  const u16* wbase = wpkd + w * 1024 + l * 8;

  // kc0-3 -> regs; slot starts as kc7
  bf16x8 wres[4][8];
#pragma unroll
  for (int c = 0; c < 4; ++c)
#pragma unroll
    for (int nt = 0; nt < 8; ++nt)
      wres[c][nt] = *(const bf16x8*)(wbase + c * 32768 + (nt >> 1) * 8192 + (nt & 1) * 512);
  bf16x8 wslot[8];
#pragma unroll
  for (int nt = 0; nt < 8; ++nt)
    wslot[nt] = *(const bf16x8*)(wbase + 7 * 32768 + (nt >> 1) * 8192 + (nt & 1) * 512);

  // kc4,5 -> LDS
#pragma unroll
  for (int jr = 0; jr < 16; ++jr)
    gload16((const char*)(wpkd + 131072) + jr * 8192 + w * 1024 + l * 16,
            (char*)swr + jr * 8192 + w * 1024);

  // zero h (both buffers) and c
  for (int i = tid; i < 8192; i += 512) ((u16*)shd)[i] = 0;
  for (int i = tid; i < 4096; i += 512) cl[i] = 0.f;

  int tgt[4];
#pragma unroll
  for (int r = 0; r < 4; ++r) tgt[r] = target[b0 + rr + r];
  const int* ip = input + (size_t)(b0 + rr) * Tx;

  int ids0[4], idsA[4], idsB[4];
#pragma unroll
  for (int r = 0; r < 4; ++r) {
    ids0[r] = ip[r * Tx + 0];
    idsA[r] = ip[r * Tx + 1];
    idsB[r] = ip[r * Tx + 2];
  }
  const int go = (w * 16 + (l & 15)) * 8;
  u16x8 xv[4];
#pragma unroll
  for (int r = 0; r < 4; ++r)
    xv[r] = *(const u16x8*)(vp + ((size_t)(ids0[r] * 2 + dir)) * 1024 + go);

  // A-fragment swizzled byte offsets: lane reads h[row=l&15][kc*32+(l>>4)*8 ..+8]
  const int arow = l & 15;
  const int aswz = (arow & 7) << 4;
  int aoff[8];
#pragma unroll
  for (int kc = 0; kc < 8; ++kc)
    aoff[kc] = (kc * 64 + ((l >> 4) << 4)) ^ aswz;
  const char* rb0 = (const char*)&shd[0][0] + arow * 512;
  const char* rb1 = (const char*)&shd[1][0] + arow * 512;
  char* wb0 = (char*)&shd[0][0];
  char* wb1 = (char*)&shd[1][0];
  const u16* swb = swr + w * 1024 + l * 8;

  __syncthreads();  // full drain once (covers gload16 staging + zeros)

#pragma unroll 1
  for (int t = 0; t < Tx; t += 2) {
    RSTEP(idsA, t, rb0, wb1);      // read buf0, write buf1
    RSTEP(idsB, t + 1, rb1, wb0);  // read buf1, write buf0
  }
}

// ---------------- output head ----------------
__global__ void k_out(const float* __restrict__ gath, const float* __restrict__ wout,
                      const float* __restrict__ bout, float* __restrict__ out) {
  int b = blockIdx.x, l = threadIdx.x;
  float s = 0.f;
  for (int j = l; j < 512; j += 64) s += gath[(size_t)b * 512 + j] * wout[j];
#pragma unroll
  for (int off = 32; off; off >>= 1) s += __shfl_down(s, off);
  if (l == 0) out[b] = 1.f / (1.f + __expf(-(s + bout[0])));
}

extern "C" void kernel_launch(void* const* d_in, const int* in_sizes, int n_in,
                              void* d_out, int out_size, void* d_ws, size_t ws_size,
                              hipStream_t stream) {
  const int* input = (const int*)d_in[0];
  const int* target = (const int*)d_in[1];
  const float* emb  = (const float*)d_in[3];
  const float* wihf = (const float*)d_in[4];
  const float* whhf = (const float*)d_in[5];
  const float* bihf = (const float*)d_in[6];
  const float* bhhf = (const float*)d_in[7];
  const float* wihb = (const float*)d_in[8];
  const float* whhb = (const float*)d_in[9];
  const float* bihb = (const float*)d_in[10];
  const float* bhhb = (const float*)d_in[11];
  const float* wout = (const float*)d_in[12];
  const float* bout = (const float*)d_in[13];
  float* out = (float*)d_out;

  char* ws = (char*)d_ws;
  u16* embbf  = (u16*)(ws + 0);          // 12,268,032 B
  u16* wih    = (u16*)(ws + 12268032);   //  3,145,728 B  [2048][768] bf16
  u16* wpk    = (u16*)(ws + 15413760);   //  1,048,576 B  packed w_hh
  float* bcat = (float*)(ws + 16462336); //      8,192 B
  float* gath = (float*)(ws + 16470528); //    524,288 B
  u16* vp     = (u16*)(ws + 16994816);   // 33,030,144 B  packed vocab proj -> ~50 MB

  k_cvt<<<1024, 256, 0, stream>>>(emb, embbf, Vx * Ex);
  k_cvt<<<512, 256, 0, stream>>>(wihf, wih, Gx * Ex);
  k_cvt<<<512, 256, 0, stream>>>(wihb, wih + Gx * Ex, Gx * Ex);
  k_bias<<<4, 256, 0, stream>>>(bihf, bhhf, bihb, bhhb, bcat);
  k_pack_whh<<<512, 256, 0, stream>>>(whhf, whhb, wpk);
  k_vproj<<<1008, 256, 0, stream>>>(embbf, wih, bcat, vp);
  k_rnn<<<32, 512, 0, stream>>>(wpk, vp, input, target, gath);
  k_out<<<256, 64, 0, stream>>>(gath, wout, bout, out);
}

// Round 5
// 1758.552 us; speedup vs baseline: 3.5567x; 1.3948x over previous
//
#include <hip/hip_runtime.h>
#include <hip/hip_bf16.h>

#define Bx 256
#define Tx 512
#define Ex 768
#define Hx 256
#define Gx 1024
#define Vx 7987

typedef unsigned short u16;
typedef unsigned int u32;
typedef __bf16 bf16;
typedef bf16 bf16x8 __attribute__((ext_vector_type(8)));
typedef u16 u16x8 __attribute__((ext_vector_type(8)));
typedef float f32x4 __attribute__((ext_vector_type(4)));

__device__ __forceinline__ u16 f2bf(float f) {
  union { float f; u32 u; } x; x.f = f;
  u32 r = x.u + 0x7fffu + ((x.u >> 16) & 1u);
  return (u16)(r >> 16);
}
__device__ __forceinline__ float bf2f(u16 b) {
  union { u32 u; float f; } x; x.u = ((u32)b) << 16;
  return x.f;
}
__device__ __forceinline__ void gload16(const void* g, void* l) {
  __builtin_amdgcn_global_load_lds((const __attribute__((address_space(1))) u32*)g,
                                   (__attribute__((address_space(3))) u32*)l, 16, 0, 0);
}
__device__ __forceinline__ float sigf(float x) {
  return __builtin_amdgcn_rcpf(1.f + __builtin_amdgcn_exp2f(x * -1.442695041f));
}
// barrier draining LDS ops only; global loads stay in flight
__device__ __forceinline__ void bar_ds() {
  __builtin_amdgcn_sched_barrier(0);
  asm volatile("s_waitcnt lgkmcnt(0)" ::: "memory");
  __builtin_amdgcn_s_barrier();
  __builtin_amdgcn_sched_barrier(0);
}
// counted vmcnt waits (never drain what we still want in flight)
#define WAITV(N) { asm volatile("s_waitcnt vmcnt(" #N ")"); __builtin_amdgcn_sched_barrier(0); }

// raw global loads with SGPR base + 32-bit VGPR offset (counted by hand)
__device__ __forceinline__ void gld8(bf16x8& d, const u16* base, u32 voff) {
  asm volatile("global_load_dwordx4 %0, %1, %2" : "=v"(d) : "v"(voff), "s"(base));
}
__device__ __forceinline__ void gld8u(u16x8& d, const u16* base, u32 voff) {
  asm volatile("global_load_dwordx4 %0, %1, %2" : "=v"(d) : "v"(voff), "s"(base));
}
__device__ __forceinline__ void gld1(int& d, const int* base, u32 voff) {
  asm volatile("global_load_dword %0, %1, %2" : "=v"(d) : "v"(voff), "s"(base));
}
// MFMA with B from VGPR / from pinned AGPR
__device__ __forceinline__ void mfma_v(f32x4& d, bf16x8 a, bf16x8 b) {
  asm volatile("v_mfma_f32_16x16x32_bf16 %0, %1, %2, %0" : "+v"(d) : "v"(a), "v"(b));
}
__device__ __forceinline__ void mfma_ag(f32x4& d, bf16x8 a, bf16x8 b) {
  asm volatile("v_mfma_f32_16x16x32_bf16 %0, %1, %2, %0" : "+v"(d) : "v"(a), "a"(b));
}

// ---------------- conversion / packing kernels ----------------

__global__ void k_cvt(const float* __restrict__ src, u16* __restrict__ dst, int n) {
  int i = blockIdx.x * blockDim.x + threadIdx.x;
  int st = gridDim.x * blockDim.x;
  for (; i < n; i += st) dst[i] = f2bf(src[i]);
}

__global__ void k_bias(const float* __restrict__ bihf, const float* __restrict__ bhhf,
                       const float* __restrict__ bihb, const float* __restrict__ bhhb,
                       float* __restrict__ bcat) {
  int i = blockIdx.x * blockDim.x + threadIdx.x;
  if (i < Gx) { bcat[i] = bihf[i] + bhhf[i]; bcat[Gx + i] = bihb[i] + bhhb[i]; }
}

// pack w_hh into fragment-linear layout:
// pk[((dir*8 + kc)*64 + nblk)*512 + lane*8 + j] = w[dir][n=nblk*16+(lane&15)][k=kc*32+(lane>>4)*8+j]
__global__ void k_pack_whh(const float* __restrict__ wf, const float* __restrict__ wb,
                           u16* __restrict__ pk) {
  int i = blockIdx.x * blockDim.x + threadIdx.x;
  int st = gridDim.x * blockDim.x;
  for (; i < 2 * 8 * 64 * 512; i += st) {
    int j = i & 7;
    int lane = (i >> 3) & 63;
    int nblk = (i >> 9) & 63;
    int kc = (i >> 15) & 7;
    int dir = i >> 18;
    int n = nblk * 16 + (lane & 15);
    int k = kc * 32 + ((lane >> 4) << 3) + j;
    const float* w = dir ? wb : wf;
    pk[i] = f2bf(w[n * Hx + k]);
  }
}

// ---------------- vocab projection GEMM (runs ONCE) ----------------
// vp[(tok*2 + dir)*1024 + (w*16 + u)*8 + g*2 + fc]
__global__ __launch_bounds__(256) void k_vproj(
    const u16* __restrict__ embbf, const u16* __restrict__ wih,
    const float* __restrict__ bcat, u16* __restrict__ vp) {
  __shared__ u16 sA[128 * 64];
  __shared__ u16 sB[128 * 64];
  const int tid = threadIdx.x;
  const int l = tid & 63, w = tid >> 6;
  const int bx = blockIdx.x & 15, by = blockIdx.x >> 4;  // by: 0..62
  const int wm = w >> 1, wn = w & 1;
  const int lr = l >> 3, lc = l & 7;

  f32x4 acc[4][4];
#pragma unroll
  for (int a = 0; a < 4; ++a)
#pragma unroll
    for (int b = 0; b < 4; ++b) acc[a][b] = f32x4{0.f, 0.f, 0.f, 0.f};

  size_t asrc[4], bsrc[4];
#pragma unroll
  for (int j = 0; j < 4; ++j) {
    int row = j * 32 + w * 8 + lr;
    int m = by * 128 + row;
    int er = (m < Vx) ? m : 0;
    asrc[j] = (size_t)er * (Ex * 2) + (size_t)((lc * 16) ^ ((row & 7) << 4));
    bsrc[j] = (size_t)(bx * 128 + row) * (Ex * 2) + (size_t)((lc * 16) ^ ((row & 7) << 4));
  }

  for (int kt = 0; kt < 12; ++kt) {
    const char* ebase = (const char*)embbf + (size_t)kt * 128;
    const char* wbase = (const char*)wih + (size_t)kt * 128;
#pragma unroll
    for (int j = 0; j < 4; ++j) {
      gload16(ebase + asrc[j], (char*)sA + (j * 32 + w * 8) * 128);
      gload16(wbase + bsrc[j], (char*)sB + (j * 32 + w * 8) * 128);
    }
    __syncthreads();
#pragma unroll
    for (int kk = 0; kk < 2; ++kk) {
      int kb = kk * 64 + ((l >> 4) * 16);
      bf16x8 av[4], bv[4];
#pragma unroll
      for (int f = 0; f < 4; ++f) {
        int r = wm * 64 + f * 16 + (l & 15);
        av[f] = *(const bf16x8*)((const char*)sA + r * 128 + (kb ^ ((r & 7) << 4)));
      }
#pragma unroll
      for (int f = 0; f < 4; ++f) {
        int n = wn * 64 + f * 16 + (l & 15);
        bv[f] = *(const bf16x8*)((const char*)sB + n * 128 + (kb ^ ((n & 7) << 4)));
      }
#pragma unroll
      for (int fm = 0; fm < 4; ++fm)
#pragma unroll
        for (int fn = 0; fn < 4; ++fn)
          acc[fm][fn] = __builtin_amdgcn_mfma_f32_16x16x32_bf16(av[fm], bv[fn], acc[fm][fn], 0, 0, 0);
    }
    __syncthreads();
  }
#pragma unroll
  for (int fn = 0; fn < 4; ++fn) {
    int col = bx * 128 + wn * 64 + fn * 16 + (l & 15);
    int dirc = col >> 10, c10 = col & 1023;
    int gq = c10 >> 8, wq = (c10 >> 5) & 7, fcq = (c10 >> 4) & 1, uq = c10 & 15;
    int pos = (wq * 16 + uq) * 8 + gq * 2 + fcq;
    float bias = bcat[col];
#pragma unroll
    for (int fm = 0; fm < 4; ++fm) {
      int m0 = by * 128 + wm * 64 + fm * 16 + ((l >> 4) << 2);
#pragma unroll
      for (int r = 0; r < 4; ++r)
        vp[((size_t)(m0 + r) * 2 + dirc) * 1024 + pos] = f2bf(acc[fm][fn][r] + bias);
    }
  }
}

// ---------------- recurrence: ONE launch, all 512 steps ----------------
// 32 blocks = 2 dirs x 16 slices (16 rows). 8 waves.
// kc0-3: AGPR-pinned (asm mfma "a"). kc4,5: LDS. kc6,7: one 32-reg slot,
// alternately refilled with >= half-step prefetch windows, counted vmcnt.
__global__ __launch_bounds__(512, 2) void k_rnn(
    const u16* __restrict__ wpk_all, const u16* __restrict__ vp,
    const int* __restrict__ input, const int* __restrict__ target,
    float* __restrict__ gath) {
  __shared__ u16 swr[65536];        // 131072 B: kc4,5
  __shared__ u16 sh[16 * 264];      // 8448 B: h, stride 528B (16B-aligned, bank-rotated)
  __shared__ float cl[16 * 256];    // 16384 B: c
  const int tid = threadIdx.x;
  const int l = tid & 63, w = tid >> 6;
  const int dir = blockIdx.x >> 4, slice = blockIdx.x & 15;
  const int b0 = slice * 16;
  const int rr = (l >> 4) << 2;
  const u16* wpkd = wpk_all + (size_t)dir * 262144;

  const u32 cvo = (u32)(w * 2048 + l * 16);  // per-lane byte offset within a chunk
  const u16* bk6[8];
  const u16* bk7[8];
#pragma unroll
  for (int nt = 0; nt < 8; ++nt) {
    int off = (nt >> 1) * 8192 + (nt & 1) * 512;  // u16 units
    bk6[nt] = wpkd + 6 * 32768 + off;
    bk7[nt] = wpkd + 7 * 32768 + off;
  }

  // kc0-3 -> to-be-AGPR (forced by "a" uses in mfma_ag)
  bf16x8 wres[4][8];
#pragma unroll
  for (int c = 0; c < 4; ++c)
#pragma unroll
    for (int nt = 0; nt < 8; ++nt)
      wres[c][nt] = *(const bf16x8*)(wpkd + c * 32768 + (nt >> 1) * 8192 + (nt & 1) * 512 + w * 1024 + l * 8);

  // kc4,5 -> LDS
#pragma unroll
  for (int jr = 0; jr < 16; ++jr)
    gload16((const char*)(wpkd + 131072) + jr * 8192 + w * 1024 + l * 16,
            (char*)swr + jr * 8192 + w * 1024);

  // zero h, c
  for (int i = tid; i < 16 * 264; i += 512) sh[i] = 0;
  for (int i = tid; i < 16 * 256; i += 512) cl[i] = 0.f;

  int tgt[4];
#pragma unroll
  for (int r = 0; r < 4; ++r) tgt[r] = target[b0 + rr + r];
  u32 tvo[4];
#pragma unroll
  for (int r = 0; r < 4; ++r) tvo[r] = (u32)((b0 + rr + r) * Tx * 4);
  const int go2 = (w * 16 + (l & 15)) * 16 + dir * 2048;  // byte offset in vp token-pair row

  int id0[4];
#pragma unroll
  for (int r = 0; r < 4; ++r) id0[r] = input[(b0 + rr + r) * Tx];  // tokens t=0

  const char* shp = (const char*)sh + (l & 15) * 528 + ((l >> 4) << 4);
  const u16* swb = swr + w * 1024 + l * 8;

  __syncthreads();  // full drain (staging + all prologue compiler loads)
  asm volatile("s_waitcnt vmcnt(0)" ::: "memory");
  __builtin_amdgcn_sched_barrier(0);

  // steady-state prologue: counted groups [vpg: 4 vp + 4 tok][B: 8 kc6]
  u16x8 xv[4];
  int ids[4];
#pragma unroll
  for (int r = 0; r < 4; ++r) gld8u(xv[r], vp, (u32)(id0[r] * 4096 + go2));
#pragma unroll
  for (int r = 0; r < 4; ++r) gld1(ids[r], input, tvo[r] + 4);  // tokens t=1
  bf16x8 slot[8];
#pragma unroll
  for (int nt = 0; nt < 8; ++nt) gld8(slot[nt], bk6[nt], cvo);

#pragma unroll 1
  for (int t = 0; t < Tx; ++t) {
    // outstanding (old->new): vpg(8), B(8)
    WAITV(8);  // xv, ids ready
    f32x4 acc[4][2];
#pragma unroll
    for (int g = 0; g < 4; ++g)
#pragma unroll
      for (int fc = 0; fc < 2; ++fc)
        acc[g][fc] = f32x4{bf2f(xv[0][g * 2 + fc]), bf2f(xv[1][g * 2 + fc]),
                           bf2f(xv[2][g * 2 + fc]), bf2f(xv[3][g * 2 + fc])};
    WAITV(0);  // slot = kc6(t)
    {
      bf16x8 a = *(const bf16x8*)(shp + 6 * 64);
#pragma unroll
      for (int nt = 0; nt < 8; ++nt) mfma_v(acc[nt >> 1][nt & 1], a, slot[nt]);
    }
    // issue refill A: slot <- kc7(t)  (consumed end of this step)
#pragma unroll
    for (int nt = 0; nt < 8; ++nt) gld8(slot[nt], bk7[nt], cvo);
    // issue vpg: vp(t+1) using ids, tok(t+2)
    {
      u32 tn4 = (u32)(((t + 2 < Tx) ? t + 2 : Tx - 1) * 4);
#pragma unroll
      for (int r = 0; r < 4; ++r) gld8u(xv[r], vp, (u32)(ids[r] * 4096 + go2));
#pragma unroll
      for (int r = 0; r < 4; ++r) gld1(ids[r], input, tvo[r] + tn4);
    }
    // kc0-3 (AGPR-resident)
#pragma unroll
    for (int c = 0; c < 4; ++c) {
      bf16x8 a = *(const bf16x8*)(shp + c * 64);
#pragma unroll
      for (int nt = 0; nt < 8; ++nt) mfma_ag(acc[nt >> 1][nt & 1], a, wres[c][nt]);
    }
    // kc4,5 (LDS)
#pragma unroll
    for (int c = 0; c < 2; ++c) {
      bf16x8 a = *(const bf16x8*)(shp + (4 + c) * 64);
#pragma unroll
      for (int nt = 0; nt < 8; ++nt) {
        bf16x8 bb = *(const bf16x8*)(swb + c * 32768 + (nt >> 1) * 8192 + (nt & 1) * 512);
        mfma_v(acc[nt >> 1][nt & 1], a, bb);
      }
    }
    bf16x8 a7 = *(const bf16x8*)(shp + 7 * 64);
    bar_ds();   // bar1: all LDS reads of h(t) done block-wide
    WAITV(8);   // refill A retired -> slot = kc7(t); vpg stays in flight
#pragma unroll
    for (int nt = 0; nt < 8; ++nt) mfma_v(acc[nt >> 1][nt & 1], a7, slot[nt]);
    asm volatile("s_nop 7\n\ts_nop 7");  // MFMA->VALU acc-read hazard margin
    // nonlinearity + state update
#pragma unroll
    for (int fc = 0; fc < 2; ++fc) {
      int u = w * 32 + fc * 16 + (l & 15);
#pragma unroll
      for (int r = 0; r < 4; ++r) {
        int row = rr + r;
        float cold = cl[row * 256 + u];
        float si = sigf(acc[0][fc][r]);
        float sf = sigf(acc[1][fc][r]);
        float tv = 2.f * sigf(2.f * acc[2][fc][r]) - 1.f;
        float so = sigf(acc[3][fc][r]);
        float cn = sf * cold + si * tv;
        float hn = so * (2.f * sigf(2.f * cn) - 1.f);
        cl[row * 256 + u] = cn;
        sh[row * 264 + u] = f2bf(hn);
        if (t == tgt[r]) gath[(size_t)(b0 + row) * 512 + dir * 256 + u] = hn;
      }
    }
    // issue refill B: slot <- kc6(t+1)  (consumed top of next step)
#pragma unroll
    for (int nt = 0; nt < 8; ++nt) gld8(slot[nt], bk6[nt], cvo);
    bar_ds();   // bar2: h(t+1) visible
  }
}

// ---------------- output head ----------------
__global__ void k_out(const float* __restrict__ gath, const float* __restrict__ wout,
                      const float* __restrict__ bout, float* __restrict__ out) {
  int b = blockIdx.x, l = threadIdx.x;
  float s = 0.f;
  for (int j = l; j < 512; j += 64) s += gath[(size_t)b * 512 + j] * wout[j];
#pragma unroll
  for (int off = 32; off; off >>= 1) s += __shfl_down(s, off);
  if (l == 0) out[b] = 1.f / (1.f + __expf(-(s + bout[0])));
}

extern "C" void kernel_launch(void* const* d_in, const int* in_sizes, int n_in,
                              void* d_out, int out_size, void* d_ws, size_t ws_size,
                              hipStream_t stream) {
  const int* input = (const int*)d_in[0];
  const int* target = (const int*)d_in[1];
  const float* emb  = (const float*)d_in[3];
  const float* wihf = (const float*)d_in[4];
  const float* whhf = (const float*)d_in[5];
  const float* bihf = (const float*)d_in[6];
  const float* bhhf = (const float*)d_in[7];
  const float* wihb = (const float*)d_in[8];
  const float* whhb = (const float*)d_in[9];
  const float* bihb = (const float*)d_in[10];
  const float* bhhb = (const float*)d_in[11];
  const float* wout = (const float*)d_in[12];
  const float* bout = (const float*)d_in[13];
  float* out = (float*)d_out;

  char* ws = (char*)d_ws;
  u16* embbf  = (u16*)(ws + 0);          // 12,268,032 B
  u16* wih    = (u16*)(ws + 12268032);   //  3,145,728 B
  u16* wpk    = (u16*)(ws + 15413760);   //  1,048,576 B
  float* bcat = (float*)(ws + 16462336); //      8,192 B
  float* gath = (float*)(ws + 16470528); //    524,288 B
  u16* vp     = (u16*)(ws + 16994816);   // 33,030,144 B

  k_cvt<<<1024, 256, 0, stream>>>(emb, embbf, Vx * Ex);
  k_cvt<<<512, 256, 0, stream>>>(wihf, wih, Gx * Ex);
  k_cvt<<<512, 256, 0, stream>>>(wihb, wih + Gx * Ex, Gx * Ex);
  k_bias<<<4, 256, 0, stream>>>(bihf, bhhf, bihb, bhhb, bcat);
  k_pack_whh<<<512, 256, 0, stream>>>(whhf, whhb, wpk);
  k_vproj<<<1008, 256, 0, stream>>>(embbf, wih, bcat, vp);
  k_rnn<<<32, 512, 0, stream>>>(wpk, vp, input, target, gath);
  k_out<<<256, 64, 0, stream>>>(gath, wout, bout, out);
}

// Round 6
// 1572.272 us; speedup vs baseline: 3.9781x; 1.1185x over previous
//
#include <hip/hip_runtime.h>
#include <hip/hip_bf16.h>

#define Bx 256
#define Tx 512
#define Ex 768
#define Hx 256
#define Gx 1024
#define Vx 7987

typedef unsigned short u16;
typedef unsigned int u32;
typedef __bf16 bf16;
typedef bf16 bf16x8 __attribute__((ext_vector_type(8)));
typedef u16 u16x8 __attribute__((ext_vector_type(8)));
typedef float f32x4 __attribute__((ext_vector_type(4)));

__device__ __forceinline__ u16 f2bf(float f) {
  union { float f; u32 u; } x; x.f = f;
  u32 r = x.u + 0x7fffu + ((x.u >> 16) & 1u);
  return (u16)(r >> 16);
}
__device__ __forceinline__ float bf2f(u16 b) {
  union { u32 u; float f; } x; x.u = ((u32)b) << 16;
  return x.f;
}
__device__ __forceinline__ void gload16(const void* g, void* l) {
  __builtin_amdgcn_global_load_lds((const __attribute__((address_space(1))) u32*)g,
                                   (__attribute__((address_space(3))) u32*)l, 16, 0, 0);
}
__device__ __forceinline__ float sigf(float x) {
  return __builtin_amdgcn_rcpf(1.f + __builtin_amdgcn_exp2f(x * -1.442695041f));
}
// barrier draining LDS ops only; global loads stay in flight
__device__ __forceinline__ void bar_ds() {
  __builtin_amdgcn_sched_barrier(0);
  asm volatile("s_waitcnt lgkmcnt(0)" ::: "memory");
  __builtin_amdgcn_s_barrier();
  __builtin_amdgcn_sched_barrier(0);
}
#define WAITV(N) { asm volatile("s_waitcnt vmcnt(" #N ")"); __builtin_amdgcn_sched_barrier(0); }

__device__ __forceinline__ void gld8(bf16x8& d, const u16* base, u32 voff) {
  asm volatile("global_load_dwordx4 %0, %1, %2" : "=v"(d) : "v"(voff), "s"(base));
}
__device__ __forceinline__ void gld8u(u16x8& d, const u16* base, u32 voff) {
  asm volatile("global_load_dwordx4 %0, %1, %2" : "=v"(d) : "v"(voff), "s"(base));
}
__device__ __forceinline__ void gld1(int& d, const int* base, u32 voff) {
  asm volatile("global_load_dword %0, %1, %2" : "=v"(d) : "v"(voff), "s"(base));
}
__device__ __forceinline__ void mfma_v(f32x4& d, bf16x8 a, bf16x8 b) {
  asm volatile("v_mfma_f32_16x16x32_bf16 %0, %1, %2, %0" : "+v"(d) : "v"(a), "v"(b));
}
__device__ __forceinline__ void mfma_ag(f32x4& d, bf16x8 a, bf16x8 b) {
  asm volatile("v_mfma_f32_16x16x32_bf16 %0, %1, %2, %0" : "+v"(d) : "v"(a), "a"(b));
}

// ---------------- conversion / packing kernels ----------------

__global__ void k_cvt(const float* __restrict__ src, u16* __restrict__ dst, int n) {
  int i = blockIdx.x * blockDim.x + threadIdx.x;
  int st = gridDim.x * blockDim.x;
  for (; i < n; i += st) dst[i] = f2bf(src[i]);
}

__global__ void k_bias(const float* __restrict__ bihf, const float* __restrict__ bhhf,
                       const float* __restrict__ bihb, const float* __restrict__ bhhb,
                       float* __restrict__ bcat) {
  int i = blockIdx.x * blockDim.x + threadIdx.x;
  if (i < Gx) { bcat[i] = bihf[i] + bhhf[i]; bcat[Gx + i] = bihb[i] + bhhb[i]; }
}

// pack w_hh fragment-linear:
// pk[((dir*8 + kc)*64 + nblk)*512 + lane*8 + j] = w[dir][n=nblk*16+(lane&15)][k=kc*32+(lane>>4)*8+j]
__global__ void k_pack_whh(const float* __restrict__ wf, const float* __restrict__ wb,
                           u16* __restrict__ pk) {
  int i = blockIdx.x * blockDim.x + threadIdx.x;
  int st = gridDim.x * blockDim.x;
  for (; i < 2 * 8 * 64 * 512; i += st) {
    int j = i & 7;
    int lane = (i >> 3) & 63;
    int nblk = (i >> 9) & 63;
    int kc = (i >> 15) & 7;
    int dir = i >> 18;
    int n = nblk * 16 + (lane & 15);
    int k = kc * 32 + ((lane >> 4) << 3) + j;
    const float* w = dir ? wb : wf;
    pk[i] = f2bf(w[n * Hx + k]);
  }
}

// ---------------- vocab projection GEMM (runs ONCE) ----------------
// vp[(tok*2 + dir)*1024 + (w*16 + u)*8 + g*2 + fc]
__global__ __launch_bounds__(256) void k_vproj(
    const u16* __restrict__ embbf, const u16* __restrict__ wih,
    const float* __restrict__ bcat, u16* __restrict__ vp) {
  __shared__ u16 sA[128 * 64];
  __shared__ u16 sB[128 * 64];
  const int tid = threadIdx.x;
  const int l = tid & 63, w = tid >> 6;
  const int bx = blockIdx.x & 15, by = blockIdx.x >> 4;  // by: 0..62
  const int wm = w >> 1, wn = w & 1;
  const int lr = l >> 3, lc = l & 7;

  f32x4 acc[4][4];
#pragma unroll
  for (int a = 0; a < 4; ++a)
#pragma unroll
    for (int b = 0; b < 4; ++b) acc[a][b] = f32x4{0.f, 0.f, 0.f, 0.f};

  size_t asrc[4], bsrc[4];
#pragma unroll
  for (int j = 0; j < 4; ++j) {
    int row = j * 32 + w * 8 + lr;
    int m = by * 128 + row;
    int er = (m < Vx) ? m : 0;
    asrc[j] = (size_t)er * (Ex * 2) + (size_t)((lc * 16) ^ ((row & 7) << 4));
    bsrc[j] = (size_t)(bx * 128 + row) * (Ex * 2) + (size_t)((lc * 16) ^ ((row & 7) << 4));
  }

  for (int kt = 0; kt < 12; ++kt) {
    const char* ebase = (const char*)embbf + (size_t)kt * 128;
    const char* wbase = (const char*)wih + (size_t)kt * 128;
#pragma unroll
    for (int j = 0; j < 4; ++j) {
      gload16(ebase + asrc[j], (char*)sA + (j * 32 + w * 8) * 128);
      gload16(wbase + bsrc[j], (char*)sB + (j * 32 + w * 8) * 128);
    }
    __syncthreads();
#pragma unroll
    for (int kk = 0; kk < 2; ++kk) {
      int kb = kk * 64 + ((l >> 4) * 16);
      bf16x8 av[4], bv[4];
#pragma unroll
      for (int f = 0; f < 4; ++f) {
        int r = wm * 64 + f * 16 + (l & 15);
        av[f] = *(const bf16x8*)((const char*)sA + r * 128 + (kb ^ ((r & 7) << 4)));
      }
#pragma unroll
      for (int f = 0; f < 4; ++f) {
        int n = wn * 64 + f * 16 + (l & 15);
        bv[f] = *(const bf16x8*)((const char*)sB + n * 128 + (kb ^ ((n & 7) << 4)));
      }
#pragma unroll
      for (int fm = 0; fm < 4; ++fm)
#pragma unroll
        for (int fn = 0; fn < 4; ++fn)
          acc[fm][fn] = __builtin_amdgcn_mfma_f32_16x16x32_bf16(av[fm], bv[fn], acc[fm][fn], 0, 0, 0);
    }
    __syncthreads();
  }
#pragma unroll
  for (int fn = 0; fn < 4; ++fn) {
    int col = bx * 128 + wn * 64 + fn * 16 + (l & 15);
    int dirc = col >> 10, c10 = col & 1023;
    int gq = c10 >> 8, wq = (c10 >> 5) & 7, fcq = (c10 >> 4) & 1, uq = c10 & 15;
    int pos = (wq * 16 + uq) * 8 + gq * 2 + fcq;
    float bias = bcat[col];
#pragma unroll
    for (int fm = 0; fm < 4; ++fm) {
      int m0 = by * 128 + wm * 64 + fm * 16 + ((l >> 4) << 2);
#pragma unroll
      for (int r = 0; r < 4; ++r)
        vp[((size_t)(m0 + r) * 2 + dirc) * 1024 + pos] = f2bf(acc[fm][fn][r] + bias);
    }
  }
}

// ---------------- recurrence: ONE launch, all 512 steps ----------------
// 32 blocks = 2 dirs x 16 slices (16 rows). 8 waves.
// kc0-3 AGPR; kc4,5 LDS; kc6,7 single streamed slot (full-window, counted vmcnt).
// h: fragment-linear double-buffered LDS (conflict-free A-reads), c: registers.
// Queue at step entry: [S6(8), V(8)]. W1=vmcnt(8)->S6; W2=vmcnt(8)->V; W3=vmcnt(0)->S7.
#define RSTEP(T, RBP, WBB) {                                                  \
  f32x4 acc[4][2];                                                            \
  _Pragma("unroll") for (int g = 0; g < 4; ++g)                               \
    _Pragma("unroll") for (int fc = 0; fc < 2; ++fc)                          \
      acc[g][fc] = f32x4{0.f, 0.f, 0.f, 0.f};                                 \
  bf16x8 a6 = *(const bf16x8*)((RBP) + 6 * 1024);                             \
  WAITV(8); /* S6 done */                                                     \
  _Pragma("unroll") for (int nt = 0; nt < 8; ++nt)                            \
    mfma_v(acc[nt >> 1][nt & 1], a6, slot[nt]);                               \
  _Pragma("unroll") for (int nt = 0; nt < 8; ++nt)  /* issue S7(t) */         \
    gld8(slot[nt], bk7[nt], cvo);                                             \
  _Pragma("unroll") for (int c = 0; c < 4; ++c) {                             \
    bf16x8 a = *(const bf16x8*)((RBP) + c * 1024);                            \
    _Pragma("unroll") for (int nt = 0; nt < 8; ++nt)                          \
      mfma_ag(acc[nt >> 1][nt & 1], a, wres[c][nt]);                          \
  }                                                                           \
  _Pragma("unroll") for (int c = 0; c < 2; ++c) {                             \
    bf16x8 a = *(const bf16x8*)((RBP) + (4 + c) * 1024);                      \
    _Pragma("unroll") for (int nt = 0; nt < 8; ++nt) {                        \
      bf16x8 bb = *(const bf16x8*)(swb + c * 32768 + (nt >> 1) * 8192 + (nt & 1) * 512); \
      mfma_v(acc[nt >> 1][nt & 1], a, bb);                                    \
    }                                                                         \
  }                                                                           \
  bf16x8 a7 = *(const bf16x8*)((RBP) + 7 * 1024);                             \
  WAITV(8); /* V done: xv,ids ready (leaves S7) */                            \
  _Pragma("unroll") for (int g = 0; g < 4; ++g)                               \
    _Pragma("unroll") for (int fc = 0; fc < 2; ++fc) {                        \
      acc[g][fc][0] += bf2f(xv[0][g * 2 + fc]);                               \
      acc[g][fc][1] += bf2f(xv[1][g * 2 + fc]);                               \
      acc[g][fc][2] += bf2f(xv[2][g * 2 + fc]);                               \
      acc[g][fc][3] += bf2f(xv[3][g * 2 + fc]);                               \
    }                                                                         \
  WAITV(0); /* S7 done (drains stray stores too) */                           \
  _Pragma("unroll") for (int nt = 0; nt < 8; ++nt)                            \
    mfma_v(acc[nt >> 1][nt & 1], a7, slot[nt]);                               \
  _Pragma("unroll") for (int nt = 0; nt < 8; ++nt)  /* issue S6(t+1) */       \
    gld8(slot[nt], bk6[nt], cvo);                                             \
  { /* issue V(t+1): vp rows for t+1, tokens for t+2 */                       \
    u32 tn4 = (u32)((((T) + 2 < Tx) ? (T) + 2 : Tx - 1) * 4);                 \
    _Pragma("unroll") for (int r = 0; r < 4; ++r)                             \
      gld8u(xv[r], vp, (u32)(ids[r] * 4096 + go2));                           \
    _Pragma("unroll") for (int r = 0; r < 4; ++r)                             \
      gld1(ids[r], input, tvo[r] + tn4);                                      \
  }                                                                           \
  asm volatile("s_nop 7\n\ts_nop 7");                                         \
  _Pragma("unroll") for (int fc = 0; fc < 2; ++fc) {                          \
    int u = w * 32 + fc * 16 + (l & 15);                                      \
    _Pragma("unroll") for (int r = 0; r < 4; ++r) {                           \
      float si = sigf(acc[0][fc][r]);                                         \
      float sf = sigf(acc[1][fc][r]);                                         \
      float tv = 2.f * sigf(2.f * acc[2][fc][r]) - 1.f;                       \
      float so = sigf(acc[3][fc][r]);                                         \
      float cn = sf * creg[fc][r] + si * tv;                                  \
      float hn = so * (2.f * sigf(2.f * cn) - 1.f);                           \
      creg[fc][r] = cn;                                                       \
      if ((T) == tgt[r]) gath[(size_t)(b0 + rr + r) * 512 + dir * 256 + u] = hn; \
      *(u16*)((WBB) + wboff + fc * 512 + r * 16) = f2bf(hn);                  \
    }                                                                         \
  }                                                                           \
  bar_ds();                                                                   \
}

__global__ __launch_bounds__(512, 2) void k_rnn(
    const u16* __restrict__ wpk_all, const u16* __restrict__ vp,
    const int* __restrict__ input, const int* __restrict__ target,
    float* __restrict__ gath) {
  __shared__ u16 swr[65536];     // 131072 B: kc4,5
  __shared__ u16 shd[2][4096];   // 2 x 8192 B: h fragment-linear, double-buffered
  const int tid = threadIdx.x;
  const int l = tid & 63, w = tid >> 6;
  const int dir = blockIdx.x >> 4, slice = blockIdx.x & 15;
  const int b0 = slice * 16;
  const int rr = (l >> 4) << 2;
  const u16* wpkd = wpk_all + (size_t)dir * 262144;

  const u32 cvo = (u32)(w * 2048 + l * 16);
  const u16* bk6[8];
  const u16* bk7[8];
#pragma unroll
  for (int nt = 0; nt < 8; ++nt) {
    int off = (nt >> 1) * 8192 + (nt & 1) * 512;
    bk6[nt] = wpkd + 6 * 32768 + off;
    bk7[nt] = wpkd + 7 * 32768 + off;
  }

  // kc0-3 -> AGPR (pinned by "a" constraint in mfma_ag)
  bf16x8 wres[4][8];
#pragma unroll
  for (int c = 0; c < 4; ++c)
#pragma unroll
    for (int nt = 0; nt < 8; ++nt)
      wres[c][nt] = *(const bf16x8*)(wpkd + c * 32768 + (nt >> 1) * 8192 + (nt & 1) * 512 + w * 1024 + l * 8);

  // kc4,5 -> LDS
#pragma unroll
  for (int jr = 0; jr < 16; ++jr)
    gload16((const char*)(wpkd + 131072) + jr * 8192 + w * 1024 + l * 16,
            (char*)swr + jr * 8192 + w * 1024);

  // zero both h buffers
  for (int i = tid; i < 8192; i += 512) ((u16*)shd)[i] = 0;

  float creg[2][4];
#pragma unroll
  for (int fc = 0; fc < 2; ++fc)
#pragma unroll
    for (int r = 0; r < 4; ++r) creg[fc][r] = 0.f;

  int tgt[4];
  u32 tvo[4];
  int id0[4];
#pragma unroll
  for (int r = 0; r < 4; ++r) {
    tgt[r] = target[b0 + rr + r];
    tvo[r] = (u32)((b0 + rr + r) * Tx * 4);
    id0[r] = input[(b0 + rr + r) * Tx];
  }
  const int go2 = (w * 16 + (l & 15)) * 16 + dir * 2048;

  // fragment-linear h addressing
  const int aoff = ((l >> 4) << 8) + ((l & 15) << 4);             // read byte offset
  const int wboff = w * 1024 + ((l & 15) >> 3) * 256 + rr * 16 + (l & 7) * 2;  // write base
  const char* rbp0 = (const char*)&shd[0][0] + aoff;
  const char* rbp1 = (const char*)&shd[1][0] + aoff;
  char* wbb0 = (char*)&shd[0][0];
  char* wbb1 = (char*)&shd[1][0];
  const u16* swb = swr + w * 1024 + l * 8;

  __syncthreads();  // LDS zeros + staging ordering
  asm volatile("s_waitcnt vmcnt(0)" ::: "memory");
  __builtin_amdgcn_sched_barrier(0);

  // prologue queue: [S6(0), V(0)]
  bf16x8 slot[8];
#pragma unroll
  for (int nt = 0; nt < 8; ++nt) gld8(slot[nt], bk6[nt], cvo);
  u16x8 xv[4];
  int ids[4];
#pragma unroll
  for (int r = 0; r < 4; ++r) gld8u(xv[r], vp, (u32)(id0[r] * 4096 + go2));
#pragma unroll
  for (int r = 0; r < 4; ++r) gld1(ids[r], input, tvo[r] + 4);

#pragma unroll 1
  for (int t = 0; t < Tx; t += 2) {
    RSTEP(t, rbp0, wbb1);
    RSTEP(t + 1, rbp1, wbb0);
  }
}

// ---------------- output head ----------------
__global__ void k_out(const float* __restrict__ gath, const float* __restrict__ wout,
                      const float* __restrict__ bout, float* __restrict__ out) {
  int b = blockIdx.x, l = threadIdx.x;
  float s = 0.f;
  for (int j = l; j < 512; j += 64) s += gath[(size_t)b * 512 + j] * wout[j];
#pragma unroll
  for (int off = 32; off; off >>= 1) s += __shfl_down(s, off);
  if (l == 0) out[b] = 1.f / (1.f + __expf(-(s + bout[0])));
}

extern "C" void kernel_launch(void* const* d_in, const int* in_sizes, int n_in,
                              void* d_out, int out_size, void* d_ws, size_t ws_size,
                              hipStream_t stream) {
  const int* input = (const int*)d_in[0];
  const int* target = (const int*)d_in[1];
  const float* emb  = (const float*)d_in[3];
  const float* wihf = (const float*)d_in[4];
  const float* whhf = (const float*)d_in[5];
  const float* bihf = (const float*)d_in[6];
  const float* bhhf = (const float*)d_in[7];
  const float* wihb = (const float*)d_in[8];
  const float* whhb = (const float*)d_in[9];
  const float* bihb = (const float*)d_in[10];
  const float* bhhb = (const float*)d_in[11];
  const float* wout = (const float*)d_in[12];
  const float* bout = (const float*)d_in[13];
  float* out = (float*)d_out;

  char* ws = (char*)d_ws;
  u16* embbf  = (u16*)(ws + 0);          // 12,268,032 B
  u16* wih    = (u16*)(ws + 12268032);   //  3,145,728 B
  u16* wpk    = (u16*)(ws + 15413760);   //  1,048,576 B
  float* bcat = (float*)(ws + 16462336); //      8,192 B
  float* gath = (float*)(ws + 16470528); //    524,288 B
  u16* vp     = (u16*)(ws + 16994816);   // 33,030,144 B

  k_cvt<<<1024, 256, 0, stream>>>(emb, embbf, Vx * Ex);
  k_cvt<<<512, 256, 0, stream>>>(wihf, wih, Gx * Ex);
  k_cvt<<<512, 256, 0, stream>>>(wihb, wih + Gx * Ex, Gx * Ex);
  k_bias<<<4, 256, 0, stream>>>(bihf, bhhf, bihb, bhhb, bcat);
  k_pack_whh<<<512, 256, 0, stream>>>(whhf, whhb, wpk);
  k_vproj<<<1008, 256, 0, stream>>>(embbf, wih, bcat, vp);
  k_rnn<<<32, 512, 0, stream>>>(wpk, vp, input, target, gath);
  k_out<<<256, 64, 0, stream>>>(gath, wout, bout, out);
}

// Round 7
// 1203.699 us; speedup vs baseline: 5.1962x; 1.3062x over previous
//
#include <hip/hip_runtime.h>
#include <hip/hip_bf16.h>

#define Bx 256
#define Tx 512
#define Ex 768
#define Hx 256
#define Gx 1024
#define Vx 7987

typedef unsigned short u16;
typedef unsigned int u32;
typedef __bf16 bf16;
typedef bf16 bf16x8 __attribute__((ext_vector_type(8)));
typedef u16 u16x8 __attribute__((ext_vector_type(8)));
typedef float f32x4 __attribute__((ext_vector_type(4)));
typedef int i32x4 __attribute__((ext_vector_type(4)));

__device__ __forceinline__ u16 f2bf(float f) {
  union { float f; u32 u; } x; x.f = f;
  u32 r = x.u + 0x7fffu + ((x.u >> 16) & 1u);
  return (u16)(r >> 16);
}
__device__ __forceinline__ float bf2f(u16 b) {
  union { u32 u; float f; } x; x.u = ((u32)b) << 16;
  return x.f;
}
__device__ __forceinline__ void gload16(const void* g, void* l) {
  __builtin_amdgcn_global_load_lds((const __attribute__((address_space(1))) u32*)g,
                                   (__attribute__((address_space(3))) u32*)l, 16, 0, 0);
}
__device__ __forceinline__ float sigf(float x) {
  return __builtin_amdgcn_rcpf(1.f + __builtin_amdgcn_exp2f(x * -1.442695041f));
}
// barrier draining LDS ops only; global loads stay in flight
__device__ __forceinline__ void bar_ds() {
  __builtin_amdgcn_sched_barrier(0);
  asm volatile("s_waitcnt lgkmcnt(0)" ::: "memory");
  __builtin_amdgcn_s_barrier();
  __builtin_amdgcn_sched_barrier(0);
}
#define WAITV(N) { asm volatile("s_waitcnt vmcnt(" #N ")"); __builtin_amdgcn_sched_barrier(0); }

__device__ __forceinline__ void gld8u(u16x8& d, const u16* base, u32 voff) {
  asm volatile("global_load_dwordx4 %0, %1, %2" : "=v"(d) : "v"(voff), "s"(base));
}
__device__ __forceinline__ void gld1(int& d, const int* base, u32 voff) {
  asm volatile("global_load_dword %0, %1, %2" : "=v"(d) : "v"(voff), "s"(base));
}
// i8 MFMA, K=64: A = h (VGPR), B = weights pinned in AGPR
__device__ __forceinline__ void mfma_i8(i32x4& d, i32x4 a, i32x4 b) {
  asm volatile("v_mfma_i32_16x16x64_i8 %0, %1, %2, %0" : "+v"(d) : "v"(a), "a"(b));
}

// ---------------- conversion / packing kernels ----------------

__global__ void k_cvt(const float* __restrict__ src, u16* __restrict__ dst, int n) {
  int i = blockIdx.x * blockDim.x + threadIdx.x;
  int st = gridDim.x * blockDim.x;
  for (; i < n; i += st) dst[i] = f2bf(src[i]);
}

__global__ void k_bias(const float* __restrict__ bihf, const float* __restrict__ bhhf,
                       const float* __restrict__ bihb, const float* __restrict__ bhhb,
                       float* __restrict__ bcat) {
  int i = blockIdx.x * blockDim.x + threadIdx.x;
  if (i < Gx) { bcat[i] = bihf[i] + bhhf[i]; bcat[Gx + i] = bihb[i] + bhhb[i]; }
}

// per-output-row absmax scale: s[row] = max|w_hh[row,:]| / 127
__global__ void k_scales(const float* __restrict__ wf, const float* __restrict__ wb,
                         float* __restrict__ s) {
  int row = blockIdx.x;  // 0..2047 (dir*1024 + n)
  const float* w = (row < Gx) ? (wf + (size_t)row * Hx) : (wb + (size_t)(row - Gx) * Hx);
  int l = threadIdx.x;
  float m = 0.f;
  for (int j = l; j < Hx; j += 64) m = fmaxf(m, fabsf(w[j]));
#pragma unroll
  for (int off = 32; off; off >>= 1) m = fmaxf(m, __shfl_down(m, off));
  if (l == 0) s[row] = fmaxf(m, 1e-20f) * (1.f / 127.f);
}

// pack w_hh -> i8 fragment-linear for v_mfma_i32_16x16x64_i8 B-operand:
// pk[(((dir*4+kc)*64 + nb)*64 + lane)*16 + j] = q(w[dir][n=nb*16+(lane&15)][k=kc*64+(lane>>4)*16+j])
__global__ void k_pack_i8(const float* __restrict__ wf, const float* __restrict__ wb,
                          const float* __restrict__ s, char* __restrict__ pk) {
  int i = blockIdx.x * 256 + threadIdx.x;  // 32768 packers x 16 B
  int lane = i & 63, nb = (i >> 6) & 63, kc = (i >> 12) & 3, dir = (i >> 14) & 1;
  int n = nb * 16 + (lane & 15);
  int k0 = kc * 64 + ((lane >> 4) << 4);
  const float* w = dir ? wb : wf;
  float inv = 1.f / s[dir * Gx + n];
  int dw[4];
#pragma unroll
  for (int d4 = 0; d4 < 4; ++d4) {
    int v = 0;
#pragma unroll
    for (int j = 0; j < 4; ++j) {
      int q = (int)rintf(w[(size_t)n * Hx + k0 + d4 * 4 + j] * inv);
      v |= (q & 255) << (8 * j);
    }
    dw[d4] = v;
  }
  *(int4*)(pk + (size_t)i * 16) = make_int4(dw[0], dw[1], dw[2], dw[3]);
}

// ---------------- vocab projection GEMM (runs ONCE, bf16) ----------------
// vp[(tok*2 + dir)*1024 + (w*16 + u)*8 + g*2 + fc]
__global__ __launch_bounds__(256) void k_vproj(
    const u16* __restrict__ embbf, const u16* __restrict__ wih,
    const float* __restrict__ bcat, u16* __restrict__ vp) {
  __shared__ u16 sA[128 * 64];
  __shared__ u16 sB[128 * 64];
  const int tid = threadIdx.x;
  const int l = tid & 63, w = tid >> 6;
  const int bx = blockIdx.x & 15, by = blockIdx.x >> 4;  // by: 0..62
  const int wm = w >> 1, wn = w & 1;
  const int lr = l >> 3, lc = l & 7;

  f32x4 acc[4][4];
#pragma unroll
  for (int a = 0; a < 4; ++a)
#pragma unroll
    for (int b = 0; b < 4; ++b) acc[a][b] = f32x4{0.f, 0.f, 0.f, 0.f};

  size_t asrc[4], bsrc[4];
#pragma unroll
  for (int j = 0; j < 4; ++j) {
    int row = j * 32 + w * 8 + lr;
    int m = by * 128 + row;
    int er = (m < Vx) ? m : 0;
    asrc[j] = (size_t)er * (Ex * 2) + (size_t)((lc * 16) ^ ((row & 7) << 4));
    bsrc[j] = (size_t)(bx * 128 + row) * (Ex * 2) + (size_t)((lc * 16) ^ ((row & 7) << 4));
  }

  for (int kt = 0; kt < 12; ++kt) {
    const char* ebase = (const char*)embbf + (size_t)kt * 128;
    const char* wbase = (const char*)wih + (size_t)kt * 128;
#pragma unroll
    for (int j = 0; j < 4; ++j) {
      gload16(ebase + asrc[j], (char*)sA + (j * 32 + w * 8) * 128);
      gload16(wbase + bsrc[j], (char*)sB + (j * 32 + w * 8) * 128);
    }
    __syncthreads();
#pragma unroll
    for (int kk = 0; kk < 2; ++kk) {
      int kb = kk * 64 + ((l >> 4) * 16);
      bf16x8 av[4], bv[4];
#pragma unroll
      for (int f = 0; f < 4; ++f) {
        int r = wm * 64 + f * 16 + (l & 15);
        av[f] = *(const bf16x8*)((const char*)sA + r * 128 + (kb ^ ((r & 7) << 4)));
      }
#pragma unroll
      for (int f = 0; f < 4; ++f) {
        int n = wn * 64 + f * 16 + (l & 15);
        bv[f] = *(const bf16x8*)((const char*)sB + n * 128 + (kb ^ ((n & 7) << 4)));
      }
#pragma unroll
      for (int fm = 0; fm < 4; ++fm)
#pragma unroll
        for (int fn = 0; fn < 4; ++fn)
          acc[fm][fn] = __builtin_amdgcn_mfma_f32_16x16x32_bf16(av[fm], bv[fn], acc[fm][fn], 0, 0, 0);
    }
    __syncthreads();
  }
#pragma unroll
  for (int fn = 0; fn < 4; ++fn) {
    int col = bx * 128 + wn * 64 + fn * 16 + (l & 15);
    int dirc = col >> 10, c10 = col & 1023;
    int gq = c10 >> 8, wq = (c10 >> 5) & 7, fcq = (c10 >> 4) & 1, uq = c10 & 15;
    int pos = (wq * 16 + uq) * 8 + gq * 2 + fcq;
    float bias = bcat[col];
#pragma unroll
    for (int fm = 0; fm < 4; ++fm) {
      int m0 = by * 128 + wm * 64 + fm * 16 + ((l >> 4) << 2);
#pragma unroll
      for (int r = 0; r < 4; ++r)
        vp[((size_t)(m0 + r) * 2 + dirc) * 1024 + pos] = f2bf(acc[fm][fn][r] + bias);
    }
  }
}

// ---------------- recurrence: ONE launch, all 512 steps ----------------
// 32 blocks = 2 dirs x 16 slices (16 rows). 8 waves, 512 thr.
// ALL w_hh resident: i8 in 128 AGPRs/lane. h: i8 frag-linear double-buffered LDS.
// c: f32 registers. x-proj: bf16 vp gather, 1-step-ahead, WAITV(0) only.
#define STEPI(T, RB, WB) {                                                    \
  i32x4 af[4];                                                                \
  _Pragma("unroll") for (int kc = 0; kc < 4; ++kc)                            \
    af[kc] = *(const i32x4*)((RB) + kc * 1024 + aoff);                        \
  i32x4 acc[8];                                                               \
  _Pragma("unroll") for (int nt = 0; nt < 8; ++nt) acc[nt] = i32x4{0, 0, 0, 0}; \
  _Pragma("unroll") for (int kc = 0; kc < 4; ++kc)                            \
    _Pragma("unroll") for (int nt = 0; nt < 8; ++nt)                          \
      mfma_i8(acc[nt], af[kc], wres[kc][nt]);                                 \
  WAITV(0); /* xv(t), ids(t+1) ready; prior gath stores drained */            \
  float ga[2][4][4]; /* [fc][r][g] */                                         \
  _Pragma("unroll") for (int fc = 0; fc < 2; ++fc)                            \
    _Pragma("unroll") for (int r = 0; r < 4; ++r)                             \
      _Pragma("unroll") for (int g = 0; g < 4; ++g)                           \
        ga[fc][r][g] = (float)acc[g * 2 + fc][r] * qs[g * 2 + fc]             \
                       + bf2f(xv[r][g * 2 + fc]);                             \
  { /* issue V(t+1): xv rows via ids(t+1), tokens t+2 -> ~full-step window */ \
    u32 tn4 = (u32)((((T) + 2 < Tx) ? (T) + 2 : Tx - 1) * 4);                 \
    _Pragma("unroll") for (int r = 0; r < 4; ++r)                             \
      gld8u(xv[r], vp, (u32)(ids[r] * 4096) + go2);                           \
    _Pragma("unroll") for (int r = 0; r < 4; ++r)                             \
      gld1(ids[r], input, tvo[r] + tn4);                                      \
  }                                                                           \
  _Pragma("unroll") for (int fc = 0; fc < 2; ++fc)                            \
    _Pragma("unroll") for (int r = 0; r < 4; ++r) {                           \
      float si = sigf(ga[fc][r][0]);                                          \
      float sf = sigf(ga[fc][r][1]);                                          \
      float tv = 2.f * sigf(2.f * ga[fc][r][2]) - 1.f;                        \
      float so = sigf(ga[fc][r][3]);                                          \
      float cn = sf * creg[fc][r] + si * tv;                                  \
      float hn = so * (2.f * sigf(2.f * cn) - 1.f);                           \
      creg[fc][r] = cn;                                                       \
      if ((T) == tgt[r])                                                      \
        gath[(size_t)(b0 + rr + r) * 512 + dir * 256 + w * 32 + fc * 16 + (l & 15)] = hn; \
      int qh = (int)rintf(hn * 127.f);                                        \
      *((WB) + wbo + fc * 256 + r * 16) = (char)qh;                           \
    }                                                                         \
  bar_ds();                                                                   \
}

__global__ __launch_bounds__(512, 2) void k_rnn(
    const char* __restrict__ wq, const float* __restrict__ wsc,
    const u16* __restrict__ vp, const int* __restrict__ input,
    const int* __restrict__ target, float* __restrict__ gath) {
  __shared__ char shd[2][4096];  // h i8 frag-linear: ((kc*4+q)*16 + row)*16 + byte
  const int tid = threadIdx.x;
  const int l = tid & 63, w = tid >> 6;
  const int dir = blockIdx.x >> 4, slice = blockIdx.x & 15;
  const int b0 = slice * 16;
  const int rr = (l >> 4) << 2;
  const char* wqd = wq + (size_t)dir * 262144;

  // all w_hh -> AGPR (pinned by "a" constraint): 4 kc x 8 nt x 16 B = 512 B/lane
  i32x4 wres[4][8];
#pragma unroll
  for (int kc = 0; kc < 4; ++kc)
#pragma unroll
    for (int nt = 0; nt < 8; ++nt) {
      int nb = (nt >> 1) * 16 + w * 2 + (nt & 1);
      wres[kc][nt] = *(const i32x4*)(wqd + ((size_t)(kc * 64 + nb) * 64 + l) * 16);
    }
  // dequant scales: qs = s_w[n] / 127
  float qs[8];
#pragma unroll
  for (int nt = 0; nt < 8; ++nt)
    qs[nt] = wsc[dir * Gx + (nt >> 1) * 256 + w * 32 + (nt & 1) * 16 + (l & 15)] * (1.f / 127.f);

  // zero both h buffers
  for (int i = tid; i < 2048; i += 512) ((int*)shd)[i] = 0;

  float creg[2][4];
#pragma unroll
  for (int fc = 0; fc < 2; ++fc)
#pragma unroll
    for (int r = 0; r < 4; ++r) creg[fc][r] = 0.f;

  int tgt[4];
  u32 tvo[4];
  int ids[4];
#pragma unroll
  for (int r = 0; r < 4; ++r) {
    tgt[r] = target[b0 + rr + r];
    tvo[r] = (u32)((b0 + rr + r) * Tx * 4);
    ids[r] = input[(b0 + rr + r) * Tx];  // tokens t=0
  }
  const u32 go2 = (u32)((w * 16 + (l & 15)) * 16 + dir * 2048);

  const int aoff = ((l >> 4) << 8) + ((l & 15) << 4);
  const int wbo = (((w >> 1) * 4 + (w & 1) * 2) * 16 + rr) * 16 + (l & 15);
  const char* rb0 = &shd[0][0];
  const char* rb1 = &shd[1][0];
  char* wb0 = &shd[0][0];
  char* wb1 = &shd[1][0];

  __syncthreads();
  asm volatile("s_waitcnt vmcnt(0)" ::: "memory");
  __builtin_amdgcn_sched_barrier(0);

  // prologue: V(0) = xv rows for t=0 + tokens t=1
  u16x8 xv[4];
#pragma unroll
  for (int r = 0; r < 4; ++r) gld8u(xv[r], vp, (u32)(ids[r] * 4096) + go2);
#pragma unroll
  for (int r = 0; r < 4; ++r) gld1(ids[r], input, tvo[r] + 4);

#pragma unroll 1
  for (int t = 0; t < Tx; t += 2) {
    STEPI(t, rb0, wb1);
    STEPI(t + 1, rb1, wb0);
  }
}

// ---------------- output head ----------------
__global__ void k_out(const float* __restrict__ gath, const float* __restrict__ wout,
                      const float* __restrict__ bout, float* __restrict__ out) {
  int b = blockIdx.x, l = threadIdx.x;
  float s = 0.f;
  for (int j = l; j < 512; j += 64) s += gath[(size_t)b * 512 + j] * wout[j];
#pragma unroll
  for (int off = 32; off; off >>= 1) s += __shfl_down(s, off);
  if (l == 0) out[b] = 1.f / (1.f + __expf(-(s + bout[0])));
}

extern "C" void kernel_launch(void* const* d_in, const int* in_sizes, int n_in,
                              void* d_out, int out_size, void* d_ws, size_t ws_size,
                              hipStream_t stream) {
  const int* input = (const int*)d_in[0];
  const int* target = (const int*)d_in[1];
  const float* emb  = (const float*)d_in[3];
  const float* wihf = (const float*)d_in[4];
  const float* whhf = (const float*)d_in[5];
  const float* bihf = (const float*)d_in[6];
  const float* bhhf = (const float*)d_in[7];
  const float* wihb = (const float*)d_in[8];
  const float* whhb = (const float*)d_in[9];
  const float* bihb = (const float*)d_in[10];
  const float* bhhb = (const float*)d_in[11];
  const float* wout = (const float*)d_in[12];
  const float* bout = (const float*)d_in[13];
  float* out = (float*)d_out;

  char* ws = (char*)d_ws;
  u16* embbf  = (u16*)(ws + 0);          // 12,268,032 B
  u16* wih    = (u16*)(ws + 12268032);   //  3,145,728 B
  char* wq    = (char*)(ws + 15413760);  //    524,288 B  i8 packed w_hh
  float* wsc  = (float*)(ws + 15938048); //      8,192 B  per-row scales
  float* bcat = (float*)(ws + 15946240); //      8,192 B
  float* gath = (float*)(ws + 15954432); //    524,288 B
  u16* vp     = (u16*)(ws + 16478720);   // 33,030,144 B  -> ~49.5 MB

  k_cvt<<<1024, 256, 0, stream>>>(emb, embbf, Vx * Ex);
  k_cvt<<<512, 256, 0, stream>>>(wihf, wih, Gx * Ex);
  k_cvt<<<512, 256, 0, stream>>>(wihb, wih + Gx * Ex, Gx * Ex);
  k_bias<<<4, 256, 0, stream>>>(bihf, bhhf, bihb, bhhb, bcat);
  k_scales<<<2048, 64, 0, stream>>>(whhf, whhb, wsc);
  k_pack_i8<<<128, 256, 0, stream>>>(whhf, whhb, wsc, wq);
  k_vproj<<<1008, 256, 0, stream>>>(embbf, wih, bcat, vp);
  k_rnn<<<32, 512, 0, stream>>>(wq, wsc, vp, input, target, gath);
  k_out<<<256, 64, 0, stream>>>(gath, wout, bout, out);
}

// Round 9
// 589.327 us; speedup vs baseline: 10.6133x; 2.0425x over previous
//
#include <hip/hip_runtime.h>
#include <hip/hip_bf16.h>

#define Bx 256
#define Tx 512
#define Ex 768
#define Hx 256
#define Gx 1024
#define Vx 7987

typedef unsigned short u16;
typedef unsigned int u32;
typedef __bf16 bf16;
typedef bf16 bf16x8 __attribute__((ext_vector_type(8)));
typedef u16 u16x8 __attribute__((ext_vector_type(8)));
typedef float f32x4 __attribute__((ext_vector_type(4)));
typedef int i32x4 __attribute__((ext_vector_type(4)));

__device__ __forceinline__ u16 f2bf(float f) {
  union { float f; u32 u; } x; x.f = f;
  u32 r = x.u + 0x7fffu + ((x.u >> 16) & 1u);
  return (u16)(r >> 16);
}
__device__ __forceinline__ float bf2f(u16 b) {
  union { u32 u; float f; } x; x.u = ((u32)b) << 16;
  return x.f;
}
__device__ __forceinline__ void gload16(const void* g, void* l) {
  __builtin_amdgcn_global_load_lds((const __attribute__((address_space(1))) u32*)g,
                                   (__attribute__((address_space(3))) u32*)l, 16, 0, 0);
}
__device__ __forceinline__ float sigf(float x) {
  return __builtin_amdgcn_rcpf(1.f + __builtin_amdgcn_exp2f(x * -1.442695041f));
}
// barrier draining LDS ops only; global loads stay in flight
__device__ __forceinline__ void bar_ds() {
  __builtin_amdgcn_sched_barrier(0);
  asm volatile("s_waitcnt lgkmcnt(0)" ::: "memory");
  __builtin_amdgcn_s_barrier();
  __builtin_amdgcn_sched_barrier(0);
}
#define WAITV(N) { asm volatile("s_waitcnt vmcnt(" #N ")"); __builtin_amdgcn_sched_barrier(0); }

__device__ __forceinline__ void gld8u(u16x8& d, const u16* base, u32 voff) {
  asm volatile("global_load_dwordx4 %0, %1, %2" : "=&v"(d) : "v"(voff), "s"(base));
}
// i8 MFMA, K=64: A = h (VGPR), B = weights pinned in AGPR
__device__ __forceinline__ void mfma_i8(i32x4& d, i32x4 a, i32x4 b) {
  asm volatile("v_mfma_i32_16x16x64_i8 %0, %1, %2, %0" : "+v"(d) : "v"(a), "a"(b));
}

// ---------------- conversion / packing kernels ----------------

__global__ void k_cvt(const float* __restrict__ src, u16* __restrict__ dst, int n) {
  int i = blockIdx.x * blockDim.x + threadIdx.x;
  int st = gridDim.x * blockDim.x;
  for (; i < n; i += st) dst[i] = f2bf(src[i]);
}

__global__ void k_bias(const float* __restrict__ bihf, const float* __restrict__ bhhf,
                       const float* __restrict__ bihb, const float* __restrict__ bhhb,
                       float* __restrict__ bcat) {
  int i = blockIdx.x * blockDim.x + threadIdx.x;
  if (i < Gx) { bcat[i] = bihf[i] + bhhf[i]; bcat[Gx + i] = bihb[i] + bhhb[i]; }
}

// per-output-row absmax scale: s[row] = max|w_hh[row,:]| / 127
__global__ void k_scales(const float* __restrict__ wf, const float* __restrict__ wb,
                         float* __restrict__ s) {
  int row = blockIdx.x;  // 0..2047 (dir*1024 + n)
  const float* w = (row < Gx) ? (wf + (size_t)row * Hx) : (wb + (size_t)(row - Gx) * Hx);
  int l = threadIdx.x;
  float m = 0.f;
  for (int j = l; j < Hx; j += 64) m = fmaxf(m, fabsf(w[j]));
#pragma unroll
  for (int off = 32; off; off >>= 1) m = fmaxf(m, __shfl_down(m, off));
  if (l == 0) s[row] = fmaxf(m, 1e-20f) * (1.f / 127.f);
}

// pack w_hh -> i8 fragment-linear for v_mfma_i32_16x16x64_i8 B-operand:
// pk[(((dir*4+kc)*64 + nb)*64 + lane)*16 + j] = q(w[dir][n=nb*16+(lane&15)][k=kc*64+(lane>>4)*16+j])
__global__ void k_pack_i8(const float* __restrict__ wf, const float* __restrict__ wb,
                          const float* __restrict__ s, char* __restrict__ pk) {
  int i = blockIdx.x * 256 + threadIdx.x;  // 32768 packers x 16 B
  int lane = i & 63, nb = (i >> 6) & 63, kc = (i >> 12) & 3, dir = (i >> 14) & 1;
  int n = nb * 16 + (lane & 15);
  int k0 = kc * 64 + ((lane >> 4) << 4);
  const float* w = dir ? wb : wf;
  float inv = 1.f / s[dir * Gx + n];
  int dw[4];
#pragma unroll
  for (int d4 = 0; d4 < 4; ++d4) {
    int v = 0;
#pragma unroll
    for (int j = 0; j < 4; ++j) {
      int q = (int)rintf(w[(size_t)n * Hx + k0 + d4 * 4 + j] * inv);
      v |= (q & 255) << (8 * j);
    }
    dw[d4] = v;
  }
  *(int4*)(pk + (size_t)i * 16) = make_int4(dw[0], dw[1], dw[2], dw[3]);
}

// ---------------- vocab projection GEMM (runs ONCE, bf16) ----------------
// vp[(tok*2 + dir)*1024 + (w*16 + u)*8 + g*2 + fc]
__global__ __launch_bounds__(256) void k_vproj(
    const u16* __restrict__ embbf, const u16* __restrict__ wih,
    const float* __restrict__ bcat, u16* __restrict__ vp) {
  __shared__ u16 sA[128 * 64];
  __shared__ u16 sB[128 * 64];
  const int tid = threadIdx.x;
  const int l = tid & 63, w = tid >> 6;
  const int bx = blockIdx.x & 15, by = blockIdx.x >> 4;  // by: 0..62
  const int wm = w >> 1, wn = w & 1;
  const int lr = l >> 3, lc = l & 7;

  f32x4 acc[4][4];
#pragma unroll
  for (int a = 0; a < 4; ++a)
#pragma unroll
    for (int b = 0; b < 4; ++b) acc[a][b] = f32x4{0.f, 0.f, 0.f, 0.f};

  size_t asrc[4], bsrc[4];
#pragma unroll
  for (int j = 0; j < 4; ++j) {
    int row = j * 32 + w * 8 + lr;
    int m = by * 128 + row;
    int er = (m < Vx) ? m : 0;
    asrc[j] = (size_t)er * (Ex * 2) + (size_t)((lc * 16) ^ ((row & 7) << 4));
    bsrc[j] = (size_t)(bx * 128 + row) * (Ex * 2) + (size_t)((lc * 16) ^ ((row & 7) << 4));
  }

  for (int kt = 0; kt < 12; ++kt) {
    const char* ebase = (const char*)embbf + (size_t)kt * 128;
    const char* wbase = (const char*)wih + (size_t)kt * 128;
#pragma unroll
    for (int j = 0; j < 4; ++j) {
      gload16(ebase + asrc[j], (char*)sA + (j * 32 + w * 8) * 128);
      gload16(wbase + bsrc[j], (char*)sB + (j * 32 + w * 8) * 128);
    }
    __syncthreads();
#pragma unroll
    for (int kk = 0; kk < 2; ++kk) {
      int kb = kk * 64 + ((l >> 4) * 16);
      bf16x8 av[4], bv[4];
#pragma unroll
      for (int f = 0; f < 4; ++f) {
        int r = wm * 64 + f * 16 + (l & 15);
        av[f] = *(const bf16x8*)((const char*)sA + r * 128 + (kb ^ ((r & 7) << 4)));
      }
#pragma unroll
      for (int f = 0; f < 4; ++f) {
        int n = wn * 64 + f * 16 + (l & 15);
        bv[f] = *(const bf16x8*)((const char*)sB + n * 128 + (kb ^ ((n & 7) << 4)));
      }
#pragma unroll
      for (int fm = 0; fm < 4; ++fm)
#pragma unroll
        for (int fn = 0; fn < 4; ++fn)
          acc[fm][fn] = __builtin_amdgcn_mfma_f32_16x16x32_bf16(av[fm], bv[fn], acc[fm][fn], 0, 0, 0);
    }
    __syncthreads();
  }
#pragma unroll
  for (int fn = 0; fn < 4; ++fn) {
    int col = bx * 128 + wn * 64 + fn * 16 + (l & 15);
    int dirc = col >> 10, c10 = col & 1023;
    int gq = c10 >> 8, wq = (c10 >> 5) & 7, fcq = (c10 >> 4) & 1, uq = c10 & 15;
    int pos = (wq * 16 + uq) * 8 + gq * 2 + fcq;
    float bias = bcat[col];
#pragma unroll
    for (int fm = 0; fm < 4; ++fm) {
      int m0 = by * 128 + wm * 64 + fm * 16 + ((l >> 4) << 2);
#pragma unroll
      for (int r = 0; r < 4; ++r)
        vp[((size_t)(m0 + r) * 2 + dirc) * 1024 + pos] = f2bf(acc[fm][fn][r] + bias);
    }
  }
}

// ---------------- recurrence: ONE launch, all 512 steps ----------------
// 128 blocks = 2 dirs x 64 slices (4 rows each). 8 waves/block.
// w_hh fully AGPR-resident (i8). h: rotated-replica frag-linear LDS, dbuf.
// Rotation: LDS A-row 4m+j holds real row (m+j)&3 -> lane's acc[.][0] is its
// own row q -> all 64 lanes run nonlin on 2 units, no shuffles.
// Pipeline: ONE WAITV(0) per step-pair (counting-proof: drains everything,
// incl. gath stores and any compiler-inserted VMEM); both next-pair vp loads
// issued at pair top -> every load has a ~2-step window.
#define STEPI(T, RB, WB, XC) {                                                \
  i32x4 acc[8];                                                               \
  _Pragma("unroll") for (int nt = 0; nt < 8; ++nt) acc[nt] = i32x4{0, 0, 0, 0}; \
  _Pragma("unroll") for (int kc = 0; kc < 4; ++kc) {                          \
    i32x4 a = *(const i32x4*)((RB) + kc * 1024 + aoff);                       \
    _Pragma("unroll") for (int nt = 0; nt < 8; ++nt)                          \
      mfma_i8(acc[nt], a, wres[kc][nt]);                                      \
  }                                                                           \
  asm volatile("s_nop 7\n\ts_nop 7");                                         \
  float ga[2][4];                                                             \
  _Pragma("unroll") for (int fc = 0; fc < 2; ++fc)                            \
    _Pragma("unroll") for (int g = 0; g < 4; ++g)                             \
      ga[fc][g] = (float)acc[g * 2 + fc][0] * qs[g * 2 + fc]                  \
                  + bf2f(XC[g * 2 + fc]);                                     \
  _Pragma("unroll") for (int fc = 0; fc < 2; ++fc) {                          \
    float si = sigf(ga[fc][0]);                                               \
    float sf = sigf(ga[fc][1]);                                               \
    float tv = 2.f * sigf(2.f * ga[fc][2]) - 1.f;                             \
    float so = sigf(ga[fc][3]);                                               \
    float cn = sf * creg[fc] + si * tv;                                       \
    float hn = so * (2.f * sigf(2.f * cn) - 1.f);                             \
    creg[fc] = cn;                                                            \
    if ((T) == tgt)                                                           \
      gath[(size_t)(b0 + q) * 512 + dir * 256 + w * 32 + fc * 16 + c] = hn;   \
    int qh = (int)rintf(hn * 127.f);                                          \
    _Pragma("unroll") for (int m = 0; m < 4; ++m)                             \
      *((WB) + wb_base + fc * 256 + m * 64 + (((q - m) & 3) << 4)) = (char)qh; \
  }                                                                           \
  bar_ds();                                                                   \
}

__global__ __launch_bounds__(512, 2) void k_rnn(
    const char* __restrict__ wq, const float* __restrict__ wsc,
    const u16* __restrict__ vp, const int* __restrict__ input,
    const int* __restrict__ target, float* __restrict__ gath) {
  __shared__ __align__(16) char shd[2][4096];  // h i8 rotated-replica, dbuf
  __shared__ int stok[2048];                   // tokens [4 rows][512 t]
  const int tid = threadIdx.x;
  const int l = tid & 63, w = tid >> 6;
  const int q = l >> 4, c = l & 15;
  const int dir = blockIdx.x >> 6, slice = blockIdx.x & 63;
  const int b0 = slice * 4;
  const char* wqd = wq + (size_t)dir * 262144;

  // all w_hh -> AGPR: 4 kc x 8 nt x 16 B = 512 B/lane = 128 AGPRs
  i32x4 wres[4][8];
#pragma unroll
  for (int kc = 0; kc < 4; ++kc)
#pragma unroll
    for (int nt = 0; nt < 8; ++nt) {
      int nb = (nt >> 1) * 16 + w * 2 + (nt & 1);
      wres[kc][nt] = *(const i32x4*)(wqd + ((size_t)(kc * 64 + nb) * 64 + l) * 16);
    }
  float qs[8];
#pragma unroll
  for (int nt = 0; nt < 8; ++nt)
    qs[nt] = wsc[dir * Gx + (nt >> 1) * 256 + w * 32 + (nt & 1) * 16 + c] * (1.f / 127.f);

  // tokens -> LDS; zero both h buffers
  for (int i = tid; i < 2048; i += 512)
    stok[i] = input[(b0 + (i >> 9)) * Tx + (i & 511)];
  for (int i = tid; i < 2048; i += 512) ((int*)shd)[i] = 0;

  float creg[2] = {0.f, 0.f};
  const int tgt = target[b0 + q];
  const u32 go2 = (u32)((w * 16 + c) * 16 + dir * 2048);
  const int tk0 = input[(b0 + q) * Tx + 0];
  const int tk1 = input[(b0 + q) * Tx + 1];

  const int aoff = (q << 8) + (c << 4);                       // A-frag read offset
  const int wb_base = (w >> 1) * 1024 + (w & 1) * 512 + c;    // h write base
  const char* rb0 = &shd[0][0];
  const char* rb1 = &shd[1][0];
  char* wb0 = &shd[0][0];
  char* wb1 = &shd[1][0];

  __syncthreads();
  asm volatile("s_waitcnt vmcnt(0)" ::: "memory");
  __builtin_amdgcn_sched_barrier(0);

  // prologue: issue xv(t=0), xv(t=1)
  u16x8 xvA, xvB;
  gld8u(xvA, vp, (u32)tk0 * 4096 + go2);
  gld8u(xvB, vp, (u32)tk1 * 4096 + go2);

#pragma unroll 1
  for (int t = 0; t < Tx; t += 2) {
    WAITV(0);  // xvA(t), xvB(t+1) landed; ALL other VMEM drained (counting-proof)
    u16x8 xcA = xvA, xcB = xvB;
    int ta = stok[q * 512 + ((t + 2 < Tx) ? t + 2 : Tx - 1)];
    int tb = stok[q * 512 + ((t + 3 < Tx) ? t + 3 : Tx - 1)];
    gld8u(xvA, vp, (u32)ta * 4096 + go2);  // full-pair window
    gld8u(xvB, vp, (u32)tb * 4096 + go2);
    STEPI(t, rb0, wb1, xcA);
    STEPI(t + 1, rb1, wb0, xcB);
  }
}

// ---------------- output head ----------------
__global__ void k_out(const float* __restrict__ gath, const float* __restrict__ wout,
                      const float* __restrict__ bout, float* __restrict__ out) {
  int b = blockIdx.x, l = threadIdx.x;
  float s = 0.f;
  for (int j = l; j < 512; j += 64) s += gath[(size_t)b * 512 + j] * wout[j];
#pragma unroll
  for (int off = 32; off; off >>= 1) s += __shfl_down(s, off);
  if (l == 0) out[b] = 1.f / (1.f + __expf(-(s + bout[0])));
}

extern "C" void kernel_launch(void* const* d_in, const int* in_sizes, int n_in,
                              void* d_out, int out_size, void* d_ws, size_t ws_size,
                              hipStream_t stream) {
  const int* input = (const int*)d_in[0];
  const int* target = (const int*)d_in[1];
  const float* emb  = (const float*)d_in[3];
  const float* wihf = (const float*)d_in[4];
  const float* whhf = (const float*)d_in[5];
  const float* bihf = (const float*)d_in[6];
  const float* bhhf = (const float*)d_in[7];
  const float* wihb = (const float*)d_in[8];
  const float* whhb = (const float*)d_in[9];
  const float* bihb = (const float*)d_in[10];
  const float* bhhb = (const float*)d_in[11];
  const float* wout = (const float*)d_in[12];
  const float* bout = (const float*)d_in[13];
  float* out = (float*)d_out;

  char* ws = (char*)d_ws;
  u16* embbf  = (u16*)(ws + 0);          // 12,268,032 B
  u16* wih    = (u16*)(ws + 12268032);   //  3,145,728 B
  char* wq    = (char*)(ws + 15413760);  //    524,288 B  i8 packed w_hh
  float* wsc  = (float*)(ws + 15938048); //      8,192 B  per-row scales
  float* bcat = (float*)(ws + 15946240); //      8,192 B
  float* gath = (float*)(ws + 15954432); //    524,288 B
  u16* vp     = (u16*)(ws + 16478720);   // 33,030,144 B  -> ~49.5 MB

  k_cvt<<<1024, 256, 0, stream>>>(emb, embbf, Vx * Ex);
  k_cvt<<<512, 256, 0, stream>>>(wihf, wih, Gx * Ex);
  k_cvt<<<512, 256, 0, stream>>>(wihb, wih + Gx * Ex, Gx * Ex);
  k_bias<<<4, 256, 0, stream>>>(bihf, bhhf, bihb, bhhb, bcat);
  k_scales<<<2048, 64, 0, stream>>>(whhf, whhb, wsc);
  k_pack_i8<<<128, 256, 0, stream>>>(whhf, whhb, wsc, wq);
  k_vproj<<<1008, 256, 0, stream>>>(embbf, wih, bcat, vp);
  k_rnn<<<128, 512, 0, stream>>>(wq, wsc, vp, input, target, gath);
  k_out<<<256, 64, 0, stream>>>(gath, wout, bout, out);
}